// Round 1
// baseline (6166.025 us; speedup 1.0000x reference)
//
#include <hip/hip_runtime.h>

namespace {

constexpr int M  = 8;
constexpr int TT = 2048;
constexpr int D  = 16;
constexpr int NSTEP = TT - 1;
constexpr int LDC = 20;   // row stride (floats) for 16-col LDS mats: 80B, 16B-aligned, bank-spread
constexpr int LDK = 12;   // row stride for 16x8 mats: 48B, 16B-aligned

__device__ __forceinline__ float4 ld4(const float* p) { return *(const float4*)p; }
__device__ __forceinline__ void st4(float* p, float4 v) { *(float4*)p = v; }
__device__ __forceinline__ float dot4(float4 a, float4 b) {
  return a.x * b.x + a.y * b.y + a.z * b.z + a.w * b.w;
}

__global__ __launch_bounds__(64)
void kalman_kernel(const float* __restrict__ xg, const float* __restrict__ Fg,
                   const float* __restrict__ Hg, const float* __restrict__ Qg,
                   const float* __restrict__ Rg, float* __restrict__ outg) {
  __shared__ __align__(16) float F_s[D][LDC];
  __shared__ __align__(16) float H_s[M][LDC];
  __shared__ __align__(16) float Q_s[D][LDC];
  __shared__ __align__(16) float R_s[M][8];
  __shared__ __align__(16) float cov[D][LDC];    // current covariance (prior)
  __shared__ __align__(16) float Abuf[D][LDC];   // A = I - K H
  __shared__ __align__(16) float T1[D][LDC];     // AC = A*cov, then FCU = F*covU
  __shared__ __align__(16) float T2[D][LDC];     // covU
  __shared__ __align__(16) float HC[M][LDC];     // H*cov
  __shared__ __align__(16) float Kmat[D][LDK];   // K (16x8)
  __shared__ __align__(16) float KR[D][LDK];     // K*R (16x8)
  __shared__ __align__(16) float meanv[D];
  __shared__ __align__(16) float mean_u[D];
  __shared__ __align__(16) float residv[M];
  __shared__ __align__(16) float obsv[M];

  const int tid = (int)threadIdx.x;
  const int b   = (int)blockIdx.x;
  const int r  = tid & 15, g  = tid >> 4;   // 16x16 mapping: row r, cols [4g,4g+4)
  const int q8 = tid >> 3, c8 = tid & 7;    // 8x8 mapping: row q8, col c8

  // ---- load constants into LDS
  for (int idx = tid; idx < D * D; idx += 64) {
    F_s[idx >> 4][idx & 15] = Fg[idx];
    Q_s[idx >> 4][idx & 15] = Qg[idx];
  }
  for (int idx = tid; idx < M * D; idx += 64) H_s[idx >> 4][idx & 15] = Hg[idx];
  if (tid < M * M) R_s[tid >> 3][tid & 7] = Rg[tid];

  // ---- init state: cov = I, mean = 0
  st4(&cov[r][4 * g], make_float4(r == 4 * g + 0 ? 1.f : 0.f,
                                  r == 4 * g + 1 ? 1.f : 0.f,
                                  r == 4 * g + 2 ? 1.f : 0.f,
                                  r == 4 * g + 3 ? 1.f : 0.f));
  if (tid < D) meanv[tid] = 0.f;

  const float* xr  = xg  + ((size_t)b * M + (size_t)(tid & 7)) * TT;
  float*       outr = outg + ((size_t)b * M + (size_t)(tid & 7)) * TT;
  float obs_reg = 0.f;
  if (tid < M) { obs_reg = xr[0]; outr[0] = 0.f; }
  __syncthreads();

  for (int t = 0; t < NSTEP; ++t) {
    if (tid < M) obsv[tid] = obs_reg;
    __syncthreads();                                        // B1
    if (tid < M) obs_reg = xr[t + 1];                       // prefetch next obs (t+1 <= 2047 valid)

    float4 ob0 = ld4(&obsv[0]), ob1 = ld4(&obsv[4]);
    bool nanb = (ob0.x != ob0.x) || (ob0.y != ob0.y) || (ob0.z != ob0.z) || (ob0.w != ob0.w) ||
                (ob1.x != ob1.x) || (ob1.y != ob1.y) || (ob1.z != ob1.z) || (ob1.w != ob1.w);

    if (!nanb) {
      // ---- resid = obs - H*mean  (mm = c8; redundant across groups, lanes<8 store)
      {
        float4 h0 = ld4(&H_s[c8][0]), h1 = ld4(&H_s[c8][4]), h2 = ld4(&H_s[c8][8]), h3 = ld4(&H_s[c8][12]);
        float4 m0 = ld4(&meanv[0]), m1 = ld4(&meanv[4]), m2 = ld4(&meanv[8]), m3 = ld4(&meanv[12]);
        float hm = dot4(h0, m0) + dot4(h1, m1) + dot4(h2, m2) + dot4(h3, m3);
        if (tid < M) residv[tid] = obsv[tid] - hm;
      }
      // ---- HC = H*cov  (row q8, cols 2*c8, 2*c8+1)
      {
        float4 h0 = ld4(&H_s[q8][0]), h1 = ld4(&H_s[q8][4]), h2 = ld4(&H_s[q8][8]), h3 = ld4(&H_s[q8][12]);
        float hk[16] = {h0.x, h0.y, h0.z, h0.w, h1.x, h1.y, h1.z, h1.w,
                        h2.x, h2.y, h2.z, h2.w, h3.x, h3.y, h3.z, h3.w};
        float a0 = 0.f, a1 = 0.f;
        #pragma unroll
        for (int k = 0; k < 16; ++k) {
          float2 cv = *(const float2*)&cov[k][2 * c8];
          a0 += hk[k] * cv.x;
          a1 += hk[k] * cv.y;
        }
        *(float2*)&HC[q8][2 * c8] = make_float2(a0, a1);
      }
      __syncthreads();                                      // B2
      // ---- S = HC*H^T + R (element per lane) ; register Gauss-Jordan: solve S*K^T = HC
      float s0, s1, s2;
      {
        float4 hc0 = ld4(&HC[q8][0]), hc1 = ld4(&HC[q8][4]), hc2 = ld4(&HC[q8][8]), hc3 = ld4(&HC[q8][12]);
        float4 hn0 = ld4(&H_s[c8][0]), hn1 = ld4(&H_s[c8][4]), hn2 = ld4(&H_s[c8][8]), hn3 = ld4(&H_s[c8][12]);
        s0 = R_s[q8][c8] + dot4(hc0, hn0) + dot4(hc1, hn1) + dot4(hc2, hn2) + dot4(hc3, hn3);
        s1 = HC[q8][c8];        // augmented RHS cols c8 and c8+8
        s2 = HC[q8][c8 + 8];
      }
      #pragma unroll
      for (int p = 0; p < 8; ++p) {
        float prow0 = __shfl(s0, (p << 3) | c8, 64);   // old pivot row, my col
        float prow1 = __shfl(s1, (p << 3) | c8, 64);
        float prow2 = __shfl(s2, (p << 3) | c8, 64);
        float pivv  = __shfl(s0, (p << 3) | p, 64);    // S[p][p]
        float fq    = __shfl(s0, (q8 << 3) | p, 64);   // my row's col-p value
        float pinv = 1.0f / pivv;
        float fac = fq * pinv;
        if (q8 == p) { s0 *= pinv; s1 *= pinv; s2 *= pinv; }
        else         { s0 -= fac * prow0; s1 -= fac * prow1; s2 -= fac * prow2; }
      }
      // K[d][m] = K^T[m][d] : lane (q8=m, c8=d-part) holds K^T[m][c8], K^T[m][c8+8]
      Kmat[c8][q8]     = s1;
      Kmat[c8 + 8][q8] = s2;
      __syncthreads();                                      // B3
      // ---- mean_u = mean + K*resid ; KR = K*R ; A = I - K*H
      {
        float4 k0 = ld4(&Kmat[r][0]), k1 = ld4(&Kmat[r][4]);
        float kq[8] = {k0.x, k0.y, k0.z, k0.w, k1.x, k1.y, k1.z, k1.w};
        float4 rs0 = ld4(&residv[0]), rs1 = ld4(&residv[4]);
        float mu = meanv[r]
                 + kq[0] * rs0.x + kq[1] * rs0.y + kq[2] * rs0.z + kq[3] * rs0.w
                 + kq[4] * rs1.x + kq[5] * rs1.y + kq[6] * rs1.z + kq[7] * rs1.w;
        if (tid < D) mean_u[tid] = mu;
        // KR cols 2g, 2g+1 (R symmetric -> read R rows)
        float4 ra0 = ld4(&R_s[2 * g][0]),     ra1 = ld4(&R_s[2 * g][4]);
        float4 rb0 = ld4(&R_s[2 * g + 1][0]), rb1 = ld4(&R_s[2 * g + 1][4]);
        float kr0 = kq[0] * ra0.x + kq[1] * ra0.y + kq[2] * ra0.z + kq[3] * ra0.w
                  + kq[4] * ra1.x + kq[5] * ra1.y + kq[6] * ra1.z + kq[7] * ra1.w;
        float kr1 = kq[0] * rb0.x + kq[1] * rb0.y + kq[2] * rb0.z + kq[3] * rb0.w
                  + kq[4] * rb1.x + kq[5] * rb1.y + kq[6] * rb1.z + kq[7] * rb1.w;
        *(float2*)&KR[r][2 * g] = make_float2(kr0, kr1);
        // A row r cols 4g..4g+3
        float a0 = (r == 4 * g + 0) ? 1.f : 0.f;
        float a1 = (r == 4 * g + 1) ? 1.f : 0.f;
        float a2 = (r == 4 * g + 2) ? 1.f : 0.f;
        float a3 = (r == 4 * g + 3) ? 1.f : 0.f;
        #pragma unroll
        for (int mm = 0; mm < 8; ++mm) {
          float4 hv = ld4(&H_s[mm][4 * g]);
          a0 -= kq[mm] * hv.x; a1 -= kq[mm] * hv.y; a2 -= kq[mm] * hv.z; a3 -= kq[mm] * hv.w;
        }
        st4(&Abuf[r][4 * g], make_float4(a0, a1, a2, a3));
      }
      __syncthreads();                                      // B4
      // ---- AC = A*cov -> T1
      {
        float4 a0 = ld4(&Abuf[r][0]), a1 = ld4(&Abuf[r][4]), a2 = ld4(&Abuf[r][8]), a3 = ld4(&Abuf[r][12]);
        float av[16] = {a0.x, a0.y, a0.z, a0.w, a1.x, a1.y, a1.z, a1.w,
                        a2.x, a2.y, a2.z, a2.w, a3.x, a3.y, a3.z, a3.w};
        float4 acc = make_float4(0.f, 0.f, 0.f, 0.f);
        #pragma unroll
        for (int k = 0; k < 16; ++k) {
          float4 cv = ld4(&cov[k][4 * g]);
          acc.x += av[k] * cv.x; acc.y += av[k] * cv.y; acc.z += av[k] * cv.z; acc.w += av[k] * cv.w;
        }
        st4(&T1[r][4 * g], acc);
      }
      __syncthreads();                                      // B5
      // ---- covU = AC*A^T + KR*K^T -> T2
      {
        float cj[4] = {0.f, 0.f, 0.f, 0.f};
        #pragma unroll
        for (int kk = 0; kk < 4; ++kk) {
          float4 acr = ld4(&T1[r][4 * kk]);
          #pragma unroll
          for (int j = 0; j < 4; ++j) {
            float4 aj = ld4(&Abuf[4 * g + j][4 * kk]);
            cj[j] += dot4(acr, aj);
          }
        }
        float4 kr0 = ld4(&KR[r][0]), kr1 = ld4(&KR[r][4]);
        #pragma unroll
        for (int j = 0; j < 4; ++j) {
          float4 kj0 = ld4(&Kmat[4 * g + j][0]), kj1 = ld4(&Kmat[4 * g + j][4]);
          cj[j] += dot4(kr0, kj0) + dot4(kr1, kj1);
        }
        st4(&T2[r][4 * g], make_float4(cj[0], cj[1], cj[2], cj[3]));
      }
    } else {
      // NaN in obs: skip update (mean_u = mean, covU = cov)
      if (tid < D) mean_u[tid] = meanv[tid];
      st4(&T2[r][4 * g], ld4(&cov[r][4 * g]));
    }
    __syncthreads();                                        // B6
    // ---- FCU = F*covU -> T1 ; mean_p = F*mean_u -> meanv
    {
      float4 f0 = ld4(&F_s[r][0]), f1 = ld4(&F_s[r][4]), f2 = ld4(&F_s[r][8]), f3 = ld4(&F_s[r][12]);
      float fv[16] = {f0.x, f0.y, f0.z, f0.w, f1.x, f1.y, f1.z, f1.w,
                      f2.x, f2.y, f2.z, f2.w, f3.x, f3.y, f3.z, f3.w};
      float4 acc = make_float4(0.f, 0.f, 0.f, 0.f);
      #pragma unroll
      for (int k = 0; k < 16; ++k) {
        float4 cv = ld4(&T2[k][4 * g]);
        acc.x += fv[k] * cv.x; acc.y += fv[k] * cv.y; acc.z += fv[k] * cv.z; acc.w += fv[k] * cv.w;
      }
      st4(&T1[r][4 * g], acc);
      float4 u0 = ld4(&mean_u[0]), u1 = ld4(&mean_u[4]), u2 = ld4(&mean_u[8]), u3 = ld4(&mean_u[12]);
      float mp = dot4(f0, u0) + dot4(f1, u1) + dot4(f2, u2) + dot4(f3, u3);
      if (tid < D) meanv[tid] = mp;
    }
    __syncthreads();                                        // B7
    // ---- cov = FCU*F^T + Q ; y = H*mean_p -> out[t+1]
    {
      float4 fc0 = ld4(&T1[r][0]), fc1 = ld4(&T1[r][4]), fc2 = ld4(&T1[r][8]), fc3 = ld4(&T1[r][12]);
      float4 qv = ld4(&Q_s[r][4 * g]);
      float cj[4];
      #pragma unroll
      for (int j = 0; j < 4; ++j) {
        float4 fj0 = ld4(&F_s[4 * g + j][0]), fj1 = ld4(&F_s[4 * g + j][4]);
        float4 fj2 = ld4(&F_s[4 * g + j][8]), fj3 = ld4(&F_s[4 * g + j][12]);
        cj[j] = dot4(fc0, fj0) + dot4(fc1, fj1) + dot4(fc2, fj2) + dot4(fc3, fj3);
      }
      st4(&cov[r][4 * g], make_float4(cj[0] + qv.x, cj[1] + qv.y, cj[2] + qv.z, cj[3] + qv.w));
      float4 h0 = ld4(&H_s[c8][0]), h1 = ld4(&H_s[c8][4]), h2 = ld4(&H_s[c8][8]), h3 = ld4(&H_s[c8][12]);
      float4 m0 = ld4(&meanv[0]), m1 = ld4(&meanv[4]), m2 = ld4(&meanv[8]), m3 = ld4(&meanv[12]);
      float yv = dot4(h0, m0) + dot4(h1, m1) + dot4(h2, m2) + dot4(h3, m3);
      if (tid < M) outr[t + 1] = yv;
    }
    __syncthreads();                                        // B8
  }
}

} // namespace

extern "C" void kernel_launch(void* const* d_in, const int* in_sizes, int n_in,
                              void* d_out, int out_size, void* d_ws, size_t ws_size,
                              hipStream_t stream) {
  const float* x = (const float*)d_in[0];
  const float* F = (const float*)d_in[1];
  const float* H = (const float*)d_in[2];
  const float* Q = (const float*)d_in[3];
  const float* R = (const float*)d_in[4];
  float* out = (float*)d_out;
  const int bs = in_sizes[0] / (M * TT);   // 512
  hipLaunchKernelGGL(kalman_kernel, dim3(bs), dim3(64), 0, stream,
                     x, F, H, Q, R, out);
}

// Round 3
// 966.508 us; speedup vs baseline: 6.3797x; 6.3797x over previous
//
#include <hip/hip_runtime.h>

namespace {

constexpr int M  = 8;
constexpr int TT = 2048;
constexpr int D  = 16;
constexpr int NSTEP = TT - 1;
constexpr int LDC = 20;
constexpr int LDK = 12;
constexpr int MINRUN = 64;
constexpr int MAXRUN = 256;
constexpr float TOL = 2.5e-6f;

__device__ __forceinline__ float4 ld4(const float* p) { return *(const float4*)p; }
__device__ __forceinline__ void st4(float* p, float4 v) { *(float4*)p = v; }
__device__ __forceinline__ float dot4(float4 a, float4 b) {
  return a.x * b.x + a.y * b.y + a.z * b.z + a.w * b.w;
}

// ============================================================================
// Phase 1: data-independent Riccati recursion, run ONCE (1 block, 1 wave).
// Emits per-step affine maps to ws:  slot s in [0,48): gh=s/24, rh=s%24
//   floats [0..7]  = Ghat[rh][8*gh .. 8*gh+7]   (Ghat = [G ; H*G], 24x16)
//   floats [8..11] = Bhat[rh][4*gh .. 4*gh+3]   (Bhat = [B ; H*B], 24x8)
// where G = F - B*H, B = F*K. Converges -> freeze & replicate.
// ============================================================================
__global__ __launch_bounds__(64)
void riccati_kernel(const float* __restrict__ Fg, const float* __restrict__ Hg,
                    const float* __restrict__ Qg, const float* __restrict__ Rg,
                    float* __restrict__ gw) {
  __shared__ __align__(16) float F_s[D][LDC], Q_s[D][LDC], H_s[M][LDC], R_s[M][8];
  __shared__ __align__(16) float P[D][LDC], Pu[D][LDC], Tm[D][LDC], HC[M][LDC];
  __shared__ __align__(16) float Km[D][LDK], Bm[24][LDK], Gm[24][LDC];

  const int tid = (int)threadIdx.x;
  const int r = tid & 15, g = tid >> 4;
  const int q8 = tid >> 3, c8 = tid & 7;

  for (int idx = tid; idx < D * D; idx += 64) {
    F_s[idx >> 4][idx & 15] = Fg[idx];
    Q_s[idx >> 4][idx & 15] = Qg[idx];
  }
  for (int idx = tid; idx < M * D; idx += 64) H_s[idx >> 4][idx & 15] = Hg[idx];
  if (tid < M * M) R_s[tid >> 3][tid & 7] = Rg[tid];
  st4(&P[r][4 * g], make_float4(r == 4 * g + 0 ? 1.f : 0.f,
                                r == 4 * g + 1 ? 1.f : 0.f,
                                r == 4 * g + 2 ? 1.f : 0.f,
                                r == 4 * g + 3 ? 1.f : 0.f));
  __syncthreads();

  int t = 0;
  for (; t < NSTEP; ++t) {
    // ---- P1: HC = H*P   (8x16, lane (q8,c8) does cols 2c8,2c8+1)
    {
      float4 h0 = ld4(&H_s[q8][0]), h1 = ld4(&H_s[q8][4]), h2 = ld4(&H_s[q8][8]), h3 = ld4(&H_s[q8][12]);
      float hk[16] = {h0.x, h0.y, h0.z, h0.w, h1.x, h1.y, h1.z, h1.w,
                      h2.x, h2.y, h2.z, h2.w, h3.x, h3.y, h3.z, h3.w};
      float a0 = 0.f, a1 = 0.f;
      #pragma unroll
      for (int k = 0; k < 16; ++k) {
        float2 cv = *(const float2*)&P[k][2 * c8];
        a0 += hk[k] * cv.x; a1 += hk[k] * cv.y;
      }
      *(float2*)&HC[q8][2 * c8] = make_float2(a0, a1);
    }
    __syncthreads();
    // ---- P2: S = HC*H^T + R ; register Gauss-Jordan -> K^T = S^-1*HC
    {
      float s0, s1, s2;
      float4 hc0 = ld4(&HC[q8][0]), hc1 = ld4(&HC[q8][4]), hc2 = ld4(&HC[q8][8]), hc3 = ld4(&HC[q8][12]);
      float4 hn0 = ld4(&H_s[c8][0]), hn1 = ld4(&H_s[c8][4]), hn2 = ld4(&H_s[c8][8]), hn3 = ld4(&H_s[c8][12]);
      s0 = R_s[q8][c8] + dot4(hc0, hn0) + dot4(hc1, hn1) + dot4(hc2, hn2) + dot4(hc3, hn3);
      s1 = HC[q8][c8];
      s2 = HC[q8][c8 + 8];
      #pragma unroll
      for (int p = 0; p < 8; ++p) {
        float prow0 = __shfl(s0, (p << 3) | c8, 64);
        float prow1 = __shfl(s1, (p << 3) | c8, 64);
        float prow2 = __shfl(s2, (p << 3) | c8, 64);
        float pivv  = __shfl(s0, (p << 3) | p, 64);
        float fq    = __shfl(s0, (q8 << 3) | p, 64);
        float pinv = 1.0f / pivv;
        float fac = fq * pinv;
        if (q8 == p) { s0 *= pinv; s1 *= pinv; s2 *= pinv; }
        else         { s0 -= fac * prow0; s1 -= fac * prow1; s2 -= fac * prow2; }
      }
      Km[c8][q8]     = s1;
      Km[c8 + 8][q8] = s2;
    }
    __syncthreads();
    // ---- P3: Pu = P - K*HC ; B = F*K  (lane (r,g))
    {
      float4 k0 = ld4(&Km[r][0]), k1 = ld4(&Km[r][4]);
      float kq[8] = {k0.x, k0.y, k0.z, k0.w, k1.x, k1.y, k1.z, k1.w};
      float4 acc = ld4(&P[r][4 * g]);
      #pragma unroll
      for (int m = 0; m < 8; ++m) {
        float4 hc = ld4(&HC[m][4 * g]);
        acc.x -= kq[m] * hc.x; acc.y -= kq[m] * hc.y; acc.z -= kq[m] * hc.z; acc.w -= kq[m] * hc.w;
      }
      st4(&Pu[r][4 * g], acc);
      float4 f0 = ld4(&F_s[r][0]), f1 = ld4(&F_s[r][4]), f2 = ld4(&F_s[r][8]), f3 = ld4(&F_s[r][12]);
      float fv[16] = {f0.x, f0.y, f0.z, f0.w, f1.x, f1.y, f1.z, f1.w,
                      f2.x, f2.y, f2.z, f2.w, f3.x, f3.y, f3.z, f3.w};
      float b0 = 0.f, b1 = 0.f;
      #pragma unroll
      for (int k = 0; k < 16; ++k) {
        float2 kv = *(const float2*)&Km[k][2 * g];
        b0 += fv[k] * kv.x; b1 += fv[k] * kv.y;
      }
      *(float2*)&Bm[r][2 * g] = make_float2(b0, b1);
    }
    __syncthreads();
    // ---- P4: T = F*Pu ; HB = H*B
    {
      float4 f0 = ld4(&F_s[r][0]), f1 = ld4(&F_s[r][4]), f2 = ld4(&F_s[r][8]), f3 = ld4(&F_s[r][12]);
      float fv[16] = {f0.x, f0.y, f0.z, f0.w, f1.x, f1.y, f1.z, f1.w,
                      f2.x, f2.y, f2.z, f2.w, f3.x, f3.y, f3.z, f3.w};
      float4 acc = make_float4(0.f, 0.f, 0.f, 0.f);
      #pragma unroll
      for (int k = 0; k < 16; ++k) {
        float4 cv = ld4(&Pu[k][4 * g]);
        acc.x += fv[k] * cv.x; acc.y += fv[k] * cv.y; acc.z += fv[k] * cv.z; acc.w += fv[k] * cv.w;
      }
      st4(&Tm[r][4 * g], acc);
      float hb = 0.f;
      #pragma unroll
      for (int k = 0; k < 16; ++k) hb += H_s[q8][k] * Bm[k][c8];
      Bm[16 + q8][c8] = hb;
    }
    __syncthreads();
    // ---- P5: P = T*F^T + Q (+conv check) ; G = F - B*H
    int conv;
    {
      float4 t0 = ld4(&Tm[r][0]), t1 = ld4(&Tm[r][4]), t2 = ld4(&Tm[r][8]), t3 = ld4(&Tm[r][12]);
      float cj[4];
      #pragma unroll
      for (int j = 0; j < 4; ++j) {
        cj[j] = dot4(t0, ld4(&F_s[4 * g + j][0])) + dot4(t1, ld4(&F_s[4 * g + j][4]))
              + dot4(t2, ld4(&F_s[4 * g + j][8])) + dot4(t3, ld4(&F_s[4 * g + j][12]));
      }
      float4 qv = ld4(&Q_s[r][4 * g]);
      float4 po = ld4(&P[r][4 * g]);
      float4 pn = make_float4(cj[0] + qv.x, cj[1] + qv.y, cj[2] + qv.z, cj[3] + qv.w);
      st4(&P[r][4 * g], pn);
      float dmax = fmaxf(fmaxf(fabsf(pn.x - po.x), fabsf(pn.y - po.y)),
                         fmaxf(fabsf(pn.z - po.z), fabsf(pn.w - po.w)));
      conv = __all(dmax <= TOL);
      float4 b0 = ld4(&Bm[r][0]), b1 = ld4(&Bm[r][4]);
      float bq[8] = {b0.x, b0.y, b0.z, b0.w, b1.x, b1.y, b1.z, b1.w};
      float4 g4 = ld4(&F_s[r][4 * g]);
      #pragma unroll
      for (int m = 0; m < 8; ++m) {
        float4 hv = ld4(&H_s[m][4 * g]);
        g4.x -= bq[m] * hv.x; g4.y -= bq[m] * hv.y; g4.z -= bq[m] * hv.z; g4.w -= bq[m] * hv.w;
      }
      st4(&Gm[r][4 * g], g4);
    }
    __syncthreads();
    // ---- P6: HG = H*G
    {
      float4 h0 = ld4(&H_s[q8][0]), h1 = ld4(&H_s[q8][4]), h2 = ld4(&H_s[q8][8]), h3 = ld4(&H_s[q8][12]);
      float hk[16] = {h0.x, h0.y, h0.z, h0.w, h1.x, h1.y, h1.z, h1.w,
                      h2.x, h2.y, h2.z, h2.w, h3.x, h3.y, h3.z, h3.w};
      float a0 = 0.f, a1 = 0.f;
      #pragma unroll
      for (int k = 0; k < 16; ++k) {
        float2 gv = *(const float2*)&Gm[k][2 * c8];
        a0 += hk[k] * gv.x; a1 += hk[k] * gv.y;
      }
      *(float2*)&Gm[16 + q8][2 * c8] = make_float2(a0, a1);
    }
    __syncthreads();
    // ---- P7: store ws[t]
    if (tid < 48) {
      int ghs = tid >= 24 ? 1 : 0;
      int rhs = tid - 24 * ghs;
      float4 v0 = ld4(&Gm[rhs][8 * ghs]);
      float4 v1 = ld4(&Gm[rhs][8 * ghs + 4]);
      float4 v2 = ld4(&Bm[rhs][4 * ghs]);
      float* p = gw + ((size_t)t * 48 + tid) * 12;
      st4(p, v0); st4(p + 4, v1); st4(p + 8, v2);
    }
    __syncthreads();
    if (t >= MAXRUN - 1 || (t >= MINRUN && conv)) break;
  }
  // ---- fill frozen steps
  if (t < NSTEP - 1) {
    float4 v0, v1, v2;
    int ghs = tid >= 24 ? 1 : 0;
    int rhs = tid - 24 * ghs;
    if (tid < 48) {
      v0 = ld4(&Gm[rhs][8 * ghs]);
      v1 = ld4(&Gm[rhs][8 * ghs + 4]);
      v2 = ld4(&Bm[rhs][4 * ghs]);
    }
    for (int tt = t + 1; tt < NSTEP; ++tt) {
      if (tid < 48) {
        float* p = gw + ((size_t)tt * 48 + tid) * 12;
        st4(p, v0); st4(p + 4, v1); st4(p + 8, v2);
      }
    }
  }
}

// ============================================================================
// Phase 2: per-batch linear recursion  zhat = Ghat*z + Bhat*u  (pure shfl,
// no LDS, no barriers). zhat rows 0..15 = z_{t+1}, rows 16..23 = y_{t+1}.
// ============================================================================
#define LDM(tt, V0, V1, V2) do { \
    const float* _p = gw + ((size_t)(tt)*48 + sl) * 12; \
    V0 = ld4(_p); V1 = ld4(_p + 4); V2 = ld4(_p + 8); \
  } while (0)

#define KSTEP(tcur, V0, V1, V2, PFCODE) do { \
    float u0 = __shfl(ureg, 4*gh+0, 64), u1 = __shfl(ureg, 4*gh+1, 64); \
    float u2 = __shfl(ureg, 4*gh+2, 64), u3 = __shfl(ureg, 4*gh+3, 64); \
    float un = 0.f; if (is_obs) un = xr[(tcur) + 1]; \
    float z0 = __shfl(zh, 8*gh+0, 64), z1 = __shfl(zh, 8*gh+1, 64); \
    float z2 = __shfl(zh, 8*gh+2, 64), z3 = __shfl(zh, 8*gh+3, 64); \
    float z4 = __shfl(zh, 8*gh+4, 64), z5 = __shfl(zh, 8*gh+5, 64); \
    float z6 = __shfl(zh, 8*gh+6, 64), z7 = __shfl(zh, 8*gh+7, 64); \
    float acca = V0.x*z0 + V0.y*z1 + V0.z*z2 + V0.w*z3 + V2.x*u0 + V2.y*u1; \
    float accb = V1.x*z4 + V1.y*z5 + V1.z*z6 + V1.w*z7 + V2.z*u2 + V2.w*u3; \
    PFCODE; \
    float acc = acca + accb; \
    acc += __shfl_xor(acc, 32, 64); \
    zh = acc; ureg = un; \
    if (is_out) outw[(tcur) + 1] = zh; \
  } while (0)

__global__ __launch_bounds__(64)
void mean_kernel(const float* __restrict__ xg, const float* __restrict__ gw,
                 float* __restrict__ outg) {
  const int tid = (int)threadIdx.x;
  const int b = (int)blockIdx.x;
  const int rh = tid & 31, gh = tid >> 5;
  const int sl = (rh < 24) ? (gh * 24 + rh) : 0;
  const bool is_obs = (tid < 8);
  const bool is_out = (gh == 0 && rh >= 16 && rh < 24);
  const float* xr = xg + ((size_t)b * M + (size_t)(tid & 7)) * TT;
  float* outw = outg + ((size_t)b * M + (size_t)(is_out ? rh - 16 : 0)) * TT;
  if (is_out) outw[0] = 0.f;

  float zh = 0.f;
  float ureg = is_obs ? xr[0] : 0.f;
  float4 Xa, Xb, Xc, Ya, Yb, Yc;
  LDM(0, Xa, Xb, Xc);
  LDM(1, Ya, Yb, Yc);

  int t = 0;
  for (; t + 1 < NSTEP; t += 2) {
    int t2 = (t + 2 < NSTEP) ? t + 2 : NSTEP - 1;
    int t3 = (t + 3 < NSTEP) ? t + 3 : NSTEP - 1;
    KSTEP(t,     Xa, Xb, Xc, LDM(t2, Xa, Xb, Xc));
    KSTEP(t + 1, Ya, Yb, Yc, LDM(t3, Ya, Yb, Yc));
  }
  for (; t < NSTEP; ++t) KSTEP(t, Xa, Xb, Xc, (void)0);
}

// ============================================================================
// Fallback (round-1 monolithic kernel) if ws is too small.
// ============================================================================
__global__ __launch_bounds__(64)
void kalman_fallback(const float* __restrict__ xg, const float* __restrict__ Fg,
                     const float* __restrict__ Hg, const float* __restrict__ Qg,
                     const float* __restrict__ Rg, float* __restrict__ outg) {
  __shared__ __align__(16) float F_s[D][LDC];
  __shared__ __align__(16) float H_s[M][LDC];
  __shared__ __align__(16) float Q_s[D][LDC];
  __shared__ __align__(16) float R_s[M][8];
  __shared__ __align__(16) float cov[D][LDC];
  __shared__ __align__(16) float Abuf[D][LDC];
  __shared__ __align__(16) float T1[D][LDC];
  __shared__ __align__(16) float T2[D][LDC];
  __shared__ __align__(16) float HC[M][LDC];
  __shared__ __align__(16) float Kmat[D][LDK];
  __shared__ __align__(16) float KR[D][LDK];
  __shared__ __align__(16) float meanv[D];
  __shared__ __align__(16) float mean_u[D];
  __shared__ __align__(16) float residv[M];
  __shared__ __align__(16) float obsv[M];

  const int tid = (int)threadIdx.x;
  const int b   = (int)blockIdx.x;
  const int r  = tid & 15, g  = tid >> 4;
  const int q8 = tid >> 3, c8 = tid & 7;

  for (int idx = tid; idx < D * D; idx += 64) {
    F_s[idx >> 4][idx & 15] = Fg[idx];
    Q_s[idx >> 4][idx & 15] = Qg[idx];
  }
  for (int idx = tid; idx < M * D; idx += 64) H_s[idx >> 4][idx & 15] = Hg[idx];
  if (tid < M * M) R_s[tid >> 3][tid & 7] = Rg[tid];

  st4(&cov[r][4 * g], make_float4(r == 4 * g + 0 ? 1.f : 0.f,
                                  r == 4 * g + 1 ? 1.f : 0.f,
                                  r == 4 * g + 2 ? 1.f : 0.f,
                                  r == 4 * g + 3 ? 1.f : 0.f));
  if (tid < D) meanv[tid] = 0.f;

  const float* xr  = xg  + ((size_t)b * M + (size_t)(tid & 7)) * TT;
  float*       outr = outg + ((size_t)b * M + (size_t)(tid & 7)) * TT;
  float obs_reg = 0.f;
  if (tid < M) { obs_reg = xr[0]; outr[0] = 0.f; }
  __syncthreads();

  for (int t = 0; t < NSTEP; ++t) {
    if (tid < M) obsv[tid] = obs_reg;
    __syncthreads();
    if (tid < M) obs_reg = xr[t + 1];

    {
      float4 h0 = ld4(&H_s[c8][0]), h1 = ld4(&H_s[c8][4]), h2 = ld4(&H_s[c8][8]), h3 = ld4(&H_s[c8][12]);
      float4 m0 = ld4(&meanv[0]), m1 = ld4(&meanv[4]), m2 = ld4(&meanv[8]), m3 = ld4(&meanv[12]);
      float hm = dot4(h0, m0) + dot4(h1, m1) + dot4(h2, m2) + dot4(h3, m3);
      if (tid < M) residv[tid] = obsv[tid] - hm;
    }
    {
      float4 h0 = ld4(&H_s[q8][0]), h1 = ld4(&H_s[q8][4]), h2 = ld4(&H_s[q8][8]), h3 = ld4(&H_s[q8][12]);
      float hk[16] = {h0.x, h0.y, h0.z, h0.w, h1.x, h1.y, h1.z, h1.w,
                      h2.x, h2.y, h2.z, h2.w, h3.x, h3.y, h3.z, h3.w};
      float a0 = 0.f, a1 = 0.f;
      #pragma unroll
      for (int k = 0; k < 16; ++k) {
        float2 cv = *(const float2*)&cov[k][2 * c8];
        a0 += hk[k] * cv.x;
        a1 += hk[k] * cv.y;
      }
      *(float2*)&HC[q8][2 * c8] = make_float2(a0, a1);
    }
    __syncthreads();
    float s0, s1, s2;
    {
      float4 hc0 = ld4(&HC[q8][0]), hc1 = ld4(&HC[q8][4]), hc2 = ld4(&HC[q8][8]), hc3 = ld4(&HC[q8][12]);
      float4 hn0 = ld4(&H_s[c8][0]), hn1 = ld4(&H_s[c8][4]), hn2 = ld4(&H_s[c8][8]), hn3 = ld4(&H_s[c8][12]);
      s0 = R_s[q8][c8] + dot4(hc0, hn0) + dot4(hc1, hn1) + dot4(hc2, hn2) + dot4(hc3, hn3);
      s1 = HC[q8][c8];
      s2 = HC[q8][c8 + 8];
    }
    #pragma unroll
    for (int p = 0; p < 8; ++p) {
      float prow0 = __shfl(s0, (p << 3) | c8, 64);
      float prow1 = __shfl(s1, (p << 3) | c8, 64);
      float prow2 = __shfl(s2, (p << 3) | c8, 64);
      float pivv  = __shfl(s0, (p << 3) | p, 64);
      float fq    = __shfl(s0, (q8 << 3) | p, 64);
      float pinv = 1.0f / pivv;
      float fac = fq * pinv;
      if (q8 == p) { s0 *= pinv; s1 *= pinv; s2 *= pinv; }
      else         { s0 -= fac * prow0; s1 -= fac * prow1; s2 -= fac * prow2; }
    }
    Kmat[c8][q8]     = s1;
    Kmat[c8 + 8][q8] = s2;
    __syncthreads();
    {
      float4 k0 = ld4(&Kmat[r][0]), k1 = ld4(&Kmat[r][4]);
      float kq[8] = {k0.x, k0.y, k0.z, k0.w, k1.x, k1.y, k1.z, k1.w};
      float4 rs0 = ld4(&residv[0]), rs1 = ld4(&residv[4]);
      float mu = meanv[r]
               + kq[0] * rs0.x + kq[1] * rs0.y + kq[2] * rs0.z + kq[3] * rs0.w
               + kq[4] * rs1.x + kq[5] * rs1.y + kq[6] * rs1.z + kq[7] * rs1.w;
      if (tid < D) mean_u[tid] = mu;
      float4 ra0 = ld4(&R_s[2 * g][0]),     ra1 = ld4(&R_s[2 * g][4]);
      float4 rb0 = ld4(&R_s[2 * g + 1][0]), rb1 = ld4(&R_s[2 * g + 1][4]);
      float kr0 = kq[0] * ra0.x + kq[1] * ra0.y + kq[2] * ra0.z + kq[3] * ra0.w
                + kq[4] * ra1.x + kq[5] * ra1.y + kq[6] * ra1.z + kq[7] * ra1.w;
      float kr1 = kq[0] * rb0.x + kq[1] * rb0.y + kq[2] * rb0.z + kq[3] * rb0.w
                + kq[4] * rb1.x + kq[5] * rb1.y + kq[6] * rb1.z + kq[7] * rb1.w;
      *(float2*)&KR[r][2 * g] = make_float2(kr0, kr1);
      float a0 = (r == 4 * g + 0) ? 1.f : 0.f;
      float a1 = (r == 4 * g + 1) ? 1.f : 0.f;
      float a2 = (r == 4 * g + 2) ? 1.f : 0.f;
      float a3 = (r == 4 * g + 3) ? 1.f : 0.f;
      #pragma unroll
      for (int mm = 0; mm < 8; ++mm) {
        float4 hv = ld4(&H_s[mm][4 * g]);
        a0 -= kq[mm] * hv.x; a1 -= kq[mm] * hv.y; a2 -= kq[mm] * hv.z; a3 -= kq[mm] * hv.w;
      }
      st4(&Abuf[r][4 * g], make_float4(a0, a1, a2, a3));
    }
    __syncthreads();
    {
      float4 a0 = ld4(&Abuf[r][0]), a1 = ld4(&Abuf[r][4]), a2 = ld4(&Abuf[r][8]), a3 = ld4(&Abuf[r][12]);
      float av[16] = {a0.x, a0.y, a0.z, a0.w, a1.x, a1.y, a1.z, a1.w,
                      a2.x, a2.y, a2.z, a2.w, a3.x, a3.y, a3.z, a3.w};
      float4 acc = make_float4(0.f, 0.f, 0.f, 0.f);
      #pragma unroll
      for (int k = 0; k < 16; ++k) {
        float4 cv = ld4(&cov[k][4 * g]);
        acc.x += av[k] * cv.x; acc.y += av[k] * cv.y; acc.z += av[k] * cv.z; acc.w += av[k] * cv.w;
      }
      st4(&T1[r][4 * g], acc);
    }
    __syncthreads();
    {
      float cj[4] = {0.f, 0.f, 0.f, 0.f};
      #pragma unroll
      for (int kk = 0; kk < 4; ++kk) {
        float4 acr = ld4(&T1[r][4 * kk]);
        #pragma unroll
        for (int j = 0; j < 4; ++j) {
          float4 aj = ld4(&Abuf[4 * g + j][4 * kk]);
          cj[j] += dot4(acr, aj);
        }
      }
      float4 kr0 = ld4(&KR[r][0]), kr1 = ld4(&KR[r][4]);
      #pragma unroll
      for (int j = 0; j < 4; ++j) {
        float4 kj0 = ld4(&Kmat[4 * g + j][0]), kj1 = ld4(&Kmat[4 * g + j][4]);
        cj[j] += dot4(kr0, kj0) + dot4(kr1, kj1);
      }
      st4(&T2[r][4 * g], make_float4(cj[0], cj[1], cj[2], cj[3]));
    }
    __syncthreads();
    {
      float4 f0 = ld4(&F_s[r][0]), f1 = ld4(&F_s[r][4]), f2 = ld4(&F_s[r][8]), f3 = ld4(&F_s[r][12]);
      float fv[16] = {f0.x, f0.y, f0.z, f0.w, f1.x, f1.y, f1.z, f1.w,
                      f2.x, f2.y, f2.z, f2.w, f3.x, f3.y, f3.z, f3.w};
      float4 acc = make_float4(0.f, 0.f, 0.f, 0.f);
      #pragma unroll
      for (int k = 0; k < 16; ++k) {
        float4 cv = ld4(&T2[k][4 * g]);
        acc.x += fv[k] * cv.x; acc.y += fv[k] * cv.y; acc.z += fv[k] * cv.z; acc.w += fv[k] * cv.w;
      }
      st4(&T1[r][4 * g], acc);
      float4 u0 = ld4(&mean_u[0]), u1 = ld4(&mean_u[4]), u2 = ld4(&mean_u[8]), u3 = ld4(&mean_u[12]);
      float mp = dot4(f0, u0) + dot4(f1, u1) + dot4(f2, u2) + dot4(f3, u3);
      if (tid < D) meanv[tid] = mp;
    }
    __syncthreads();
    {
      float4 fc0 = ld4(&T1[r][0]), fc1 = ld4(&T1[r][4]), fc2 = ld4(&T1[r][8]), fc3 = ld4(&T1[r][12]);
      float4 qv = ld4(&Q_s[r][4 * g]);
      float cj[4];
      #pragma unroll
      for (int j = 0; j < 4; ++j) {
        float4 fj0 = ld4(&F_s[4 * g + j][0]), fj1 = ld4(&F_s[4 * g + j][4]);
        float4 fj2 = ld4(&F_s[4 * g + j][8]), fj3 = ld4(&F_s[4 * g + j][12]);
        cj[j] = dot4(fc0, fj0) + dot4(fc1, fj1) + dot4(fc2, fj2) + dot4(fc3, fj3);
      }
      st4(&cov[r][4 * g], make_float4(cj[0] + qv.x, cj[1] + qv.y, cj[2] + qv.z, cj[3] + qv.w));
      float4 h0 = ld4(&H_s[c8][0]), h1 = ld4(&H_s[c8][4]), h2 = ld4(&H_s[c8][8]), h3 = ld4(&H_s[c8][12]);
      float4 m0 = ld4(&meanv[0]), m1 = ld4(&meanv[4]), m2 = ld4(&meanv[8]), m3 = ld4(&meanv[12]);
      float yv = dot4(h0, m0) + dot4(h1, m1) + dot4(h2, m2) + dot4(h3, m3);
      if (tid < M) outr[t + 1] = yv;
    }
    __syncthreads();
  }
}

} // namespace

extern "C" void kernel_launch(void* const* d_in, const int* in_sizes, int n_in,
                              void* d_out, int out_size, void* d_ws, size_t ws_size,
                              hipStream_t stream) {
  const float* x = (const float*)d_in[0];
  const float* F = (const float*)d_in[1];
  const float* H = (const float*)d_in[2];
  const float* Q = (const float*)d_in[3];
  const float* R = (const float*)d_in[4];
  float* out = (float*)d_out;
  const int bs = in_sizes[0] / (M * TT);

  const size_t need = (size_t)NSTEP * 48 * 12 * sizeof(float);
  if (ws_size >= need) {
    float* gw = (float*)d_ws;
    hipLaunchKernelGGL(riccati_kernel, dim3(1), dim3(64), 0, stream, F, H, Q, R, gw);
    hipLaunchKernelGGL(mean_kernel, dim3(bs), dim3(64), 0, stream, x, gw, out);
  } else {
    hipLaunchKernelGGL(kalman_fallback, dim3(bs), dim3(64), 0, stream,
                       x, F, H, Q, R, out);
  }
}

// Round 4
// 415.343 us; speedup vs baseline: 14.8456x; 2.3270x over previous
//
#include <hip/hip_runtime.h>

namespace {

constexpr int M  = 8;
constexpr int TT = 2048;
constexpr int D  = 16;
constexpr int NSTEP = TT - 1;
constexpr int LDC = 20;
constexpr int LDK = 12;
constexpr int MINRUN = 64;
constexpr int MAXRUN = 256;
constexpr float TOL = 2.5e-6f;

// workspace layout (floats)
constexpr int GAIN_STRIDE = 768;               // per-t: 24 rows x 32 (16 G | 8 B | pad)
constexpr int PAD = 8;
constexpr int GAIN_SLOTS = MAXRUN + PAD;       // 264
constexpr int COMP_OFF = GAIN_SLOTS * GAIN_STRIDE;   // 202752
constexpr int HDR_OFF = COMP_OFF + 48 * 64;          // 205824
constexpr size_t WS_NEED = (size_t)(HDR_OFF + 16) * sizeof(float);

__device__ __forceinline__ float4 ld4(const float* p) { return *(const float4*)p; }
__device__ __forceinline__ void st4(float* p, float4 v) { *(float4*)p = v; }
__device__ __forceinline__ float dot4(float4 a, float4 b) {
  return a.x * b.x + a.y * b.y + a.z * b.z + a.w * b.w;
}
__device__ __forceinline__ float rdlane(float v, int l) {
  return __uint_as_float((unsigned)__builtin_amdgcn_readlane((int)__float_as_uint(v), l));
}

// generic one-time LDS matmul helper (64 lanes cooperate)
__device__ void mm_lds(const float* A, int lda, const float* B, int ldb,
                       float* C, int ldc, int n, int kk, int mcols, int tid) {
  for (int idx = tid; idx < n * mcols; idx += 64) {
    int i = idx / mcols, j = idx - i * mcols;
    float s = 0.f;
    for (int k2 = 0; k2 < kk; ++k2) s += A[i * lda + k2] * B[k2 * ldb + j];
    C[i * ldc + j] = s;
  }
}

// ============================================================================
// Phase 1: data-independent Riccati, ONE block/wave. Per-step gains to gw
// (row-major, 24 rows x 32 floats per t). On convergence: write 4-step
// composite W (48x48, padded to 48x64) + header na. No frozen-fill loop.
// ============================================================================
__global__ __launch_bounds__(64)
void riccati_kernel(const float* __restrict__ Fg, const float* __restrict__ Hg,
                    const float* __restrict__ Qg, const float* __restrict__ Rg,
                    float* __restrict__ gw) {
  __shared__ __align__(16) float F_s[D][LDC], Q_s[D][LDC], H_s[M][LDC], R_s[M][8];
  __shared__ __align__(16) float P[D][LDC], Pu[D][LDC], Tm[D][LDC], HC[M][LDC];
  __shared__ __align__(16) float Km[D][LDK], Bm[24][LDK], Gm[24][LDC];
  // composite-prep scratch
  __shared__ __align__(16) float G2s[16][16], G3s[16][16], G4s[16][16];
  __shared__ __align__(16) float P1s[16][8], P2s[16][8], P3s[16][8];
  __shared__ __align__(16) float M1s[8][16], M2s[8][16], M3s[8][16];
  __shared__ __align__(16) float S0s[8][8], S1s[8][8], S2s[8][8];

  const int tid = (int)threadIdx.x;
  const int r = tid & 15, g = tid >> 4;
  const int q8 = tid >> 3, c8 = tid & 7;

  for (int idx = tid; idx < D * D; idx += 64) {
    F_s[idx >> 4][idx & 15] = Fg[idx];
    Q_s[idx >> 4][idx & 15] = Qg[idx];
  }
  for (int idx = tid; idx < M * D; idx += 64) H_s[idx >> 4][idx & 15] = Hg[idx];
  if (tid < M * M) R_s[tid >> 3][tid & 7] = Rg[tid];
  st4(&P[r][4 * g], make_float4(r == 4 * g + 0 ? 1.f : 0.f,
                                r == 4 * g + 1 ? 1.f : 0.f,
                                r == 4 * g + 2 ? 1.f : 0.f,
                                r == 4 * g + 3 ? 1.f : 0.f));
  __syncthreads();

  int t = 0;
  for (; t < NSTEP; ++t) {
    // P1: HC = H*P
    {
      float4 h0 = ld4(&H_s[q8][0]), h1 = ld4(&H_s[q8][4]), h2 = ld4(&H_s[q8][8]), h3 = ld4(&H_s[q8][12]);
      float hk[16] = {h0.x, h0.y, h0.z, h0.w, h1.x, h1.y, h1.z, h1.w,
                      h2.x, h2.y, h2.z, h2.w, h3.x, h3.y, h3.z, h3.w};
      float a0 = 0.f, a1 = 0.f;
      #pragma unroll
      for (int k = 0; k < 16; ++k) {
        float2 cv = *(const float2*)&P[k][2 * c8];
        a0 += hk[k] * cv.x; a1 += hk[k] * cv.y;
      }
      *(float2*)&HC[q8][2 * c8] = make_float2(a0, a1);
    }
    __syncthreads();
    // P2: S = HC*H^T + R ; register Gauss-Jordan -> K^T
    {
      float s0, s1, s2;
      float4 hc0 = ld4(&HC[q8][0]), hc1 = ld4(&HC[q8][4]), hc2 = ld4(&HC[q8][8]), hc3 = ld4(&HC[q8][12]);
      float4 hn0 = ld4(&H_s[c8][0]), hn1 = ld4(&H_s[c8][4]), hn2 = ld4(&H_s[c8][8]), hn3 = ld4(&H_s[c8][12]);
      s0 = R_s[q8][c8] + dot4(hc0, hn0) + dot4(hc1, hn1) + dot4(hc2, hn2) + dot4(hc3, hn3);
      s1 = HC[q8][c8];
      s2 = HC[q8][c8 + 8];
      #pragma unroll
      for (int p = 0; p < 8; ++p) {
        float prow0 = __shfl(s0, (p << 3) | c8, 64);
        float prow1 = __shfl(s1, (p << 3) | c8, 64);
        float prow2 = __shfl(s2, (p << 3) | c8, 64);
        float pivv  = __shfl(s0, (p << 3) | p, 64);
        float fq    = __shfl(s0, (q8 << 3) | p, 64);
        float pinv = 1.0f / pivv;
        float fac = fq * pinv;
        if (q8 == p) { s0 *= pinv; s1 *= pinv; s2 *= pinv; }
        else         { s0 -= fac * prow0; s1 -= fac * prow1; s2 -= fac * prow2; }
      }
      Km[c8][q8]     = s1;
      Km[c8 + 8][q8] = s2;
    }
    __syncthreads();
    // P3: Pu = P - K*HC ; B = F*K
    {
      float4 k0 = ld4(&Km[r][0]), k1 = ld4(&Km[r][4]);
      float kq[8] = {k0.x, k0.y, k0.z, k0.w, k1.x, k1.y, k1.z, k1.w};
      float4 acc = ld4(&P[r][4 * g]);
      #pragma unroll
      for (int m = 0; m < 8; ++m) {
        float4 hc = ld4(&HC[m][4 * g]);
        acc.x -= kq[m] * hc.x; acc.y -= kq[m] * hc.y; acc.z -= kq[m] * hc.z; acc.w -= kq[m] * hc.w;
      }
      st4(&Pu[r][4 * g], acc);
      float4 f0 = ld4(&F_s[r][0]), f1 = ld4(&F_s[r][4]), f2 = ld4(&F_s[r][8]), f3 = ld4(&F_s[r][12]);
      float fv[16] = {f0.x, f0.y, f0.z, f0.w, f1.x, f1.y, f1.z, f1.w,
                      f2.x, f2.y, f2.z, f2.w, f3.x, f3.y, f3.z, f3.w};
      float b0 = 0.f, b1 = 0.f;
      #pragma unroll
      for (int k = 0; k < 16; ++k) {
        float2 kv = *(const float2*)&Km[k][2 * g];
        b0 += fv[k] * kv.x; b1 += fv[k] * kv.y;
      }
      *(float2*)&Bm[r][2 * g] = make_float2(b0, b1);
    }
    __syncthreads();
    // P4: T = F*Pu ; HB = H*B
    {
      float4 f0 = ld4(&F_s[r][0]), f1 = ld4(&F_s[r][4]), f2 = ld4(&F_s[r][8]), f3 = ld4(&F_s[r][12]);
      float fv[16] = {f0.x, f0.y, f0.z, f0.w, f1.x, f1.y, f1.z, f1.w,
                      f2.x, f2.y, f2.z, f2.w, f3.x, f3.y, f3.z, f3.w};
      float4 acc = make_float4(0.f, 0.f, 0.f, 0.f);
      #pragma unroll
      for (int k = 0; k < 16; ++k) {
        float4 cv = ld4(&Pu[k][4 * g]);
        acc.x += fv[k] * cv.x; acc.y += fv[k] * cv.y; acc.z += fv[k] * cv.z; acc.w += fv[k] * cv.w;
      }
      st4(&Tm[r][4 * g], acc);
      float hb = 0.f;
      #pragma unroll
      for (int k = 0; k < 16; ++k) hb += H_s[q8][k] * Bm[k][c8];
      Bm[16 + q8][c8] = hb;
    }
    __syncthreads();
    // P5: P' = T*F^T + Q (+conv) ; G = F - B*H
    int conv;
    {
      float4 t0 = ld4(&Tm[r][0]), t1 = ld4(&Tm[r][4]), t2 = ld4(&Tm[r][8]), t3 = ld4(&Tm[r][12]);
      float cj[4];
      #pragma unroll
      for (int j = 0; j < 4; ++j) {
        cj[j] = dot4(t0, ld4(&F_s[4 * g + j][0])) + dot4(t1, ld4(&F_s[4 * g + j][4]))
              + dot4(t2, ld4(&F_s[4 * g + j][8])) + dot4(t3, ld4(&F_s[4 * g + j][12]));
      }
      float4 qv = ld4(&Q_s[r][4 * g]);
      float4 po = ld4(&P[r][4 * g]);
      float4 pn = make_float4(cj[0] + qv.x, cj[1] + qv.y, cj[2] + qv.z, cj[3] + qv.w);
      st4(&P[r][4 * g], pn);
      float dmax = fmaxf(fmaxf(fabsf(pn.x - po.x), fabsf(pn.y - po.y)),
                         fmaxf(fabsf(pn.z - po.z), fabsf(pn.w - po.w)));
      conv = __all(dmax <= TOL);
      float4 b0 = ld4(&Bm[r][0]), b1 = ld4(&Bm[r][4]);
      float bq[8] = {b0.x, b0.y, b0.z, b0.w, b1.x, b1.y, b1.z, b1.w};
      float4 g4 = ld4(&F_s[r][4 * g]);
      #pragma unroll
      for (int m = 0; m < 8; ++m) {
        float4 hv = ld4(&H_s[m][4 * g]);
        g4.x -= bq[m] * hv.x; g4.y -= bq[m] * hv.y; g4.z -= bq[m] * hv.z; g4.w -= bq[m] * hv.w;
      }
      st4(&Gm[r][4 * g], g4);
    }
    __syncthreads();
    // P6: HG = H*G
    {
      float4 h0 = ld4(&H_s[q8][0]), h1 = ld4(&H_s[q8][4]), h2 = ld4(&H_s[q8][8]), h3 = ld4(&H_s[q8][12]);
      float hk[16] = {h0.x, h0.y, h0.z, h0.w, h1.x, h1.y, h1.z, h1.w,
                      h2.x, h2.y, h2.z, h2.w, h3.x, h3.y, h3.z, h3.w};
      float a0 = 0.f, a1 = 0.f;
      #pragma unroll
      for (int k = 0; k < 16; ++k) {
        float2 gv = *(const float2*)&Gm[k][2 * c8];
        a0 += hk[k] * gv.x; a1 += hk[k] * gv.y;
      }
      *(float2*)&Gm[16 + q8][2 * c8] = make_float2(a0, a1);
    }
    __syncthreads();
    // P7: store per-step gains, row-major: gw[t*768 + r*32 + {0..15 G, 16..23 B}]
    if (tid < 24) {
      float* p = gw + (size_t)t * GAIN_STRIDE + tid * 32;
      st4(p + 0,  ld4(&Gm[tid][0]));
      st4(p + 4,  ld4(&Gm[tid][4]));
      st4(p + 8,  ld4(&Gm[tid][8]));
      st4(p + 12, ld4(&Gm[tid][12]));
      st4(p + 16, ld4(&Bm[tid][0]));
      st4(p + 20, ld4(&Bm[tid][4]));
    }
    __syncthreads();
    if (t >= MAXRUN - 1 || (t >= MINRUN && conv)) break;
  }
  const int na = t + 1;   // gains stored for t in [0, na)

  // pad PAD extra frozen slots (covers phase-A prefetch overrun)
  if (tid < 24) {
    float4 v0 = ld4(&Gm[tid][0]), v1 = ld4(&Gm[tid][4]);
    float4 v2 = ld4(&Gm[tid][8]), v3 = ld4(&Gm[tid][12]);
    float4 v4 = ld4(&Bm[tid][0]), v5 = ld4(&Bm[tid][4]);
    for (int tt = na; tt < na + PAD; ++tt) {
      float* p = gw + (size_t)tt * GAIN_STRIDE + tid * 32;
      st4(p, v0); st4(p + 4, v1); st4(p + 8, v2);
      st4(p + 12, v3); st4(p + 16, v4); st4(p + 20, v5);
    }
  }

  // ---- composite prep: powers/products of frozen G (Gm rows 0..15, stride LDC),
  // Gy = Gm rows 16..23, B = Bm rows 0..15 (stride LDK), By = Bm rows 16..23.
  __syncthreads();
  mm_lds(&Gm[0][0], LDC, &Gm[0][0], LDC, &G2s[0][0], 16, 16, 16, 16, tid);  // G^2
  mm_lds(&Gm[0][0], LDC, &Bm[0][0], LDK, &P1s[0][0], 8, 16, 16, 8, tid);    // G B
  mm_lds(&Gm[16][0], LDC, &Gm[0][0], LDC, &M1s[0][0], 16, 8, 16, 16, tid);  // Gy G
  mm_lds(&Gm[16][0], LDC, &Bm[0][0], LDK, &S0s[0][0], 8, 8, 16, 8, tid);    // Gy B
  __syncthreads();
  mm_lds(&G2s[0][0], 16, &Gm[0][0], LDC, &G3s[0][0], 16, 16, 16, 16, tid);  // G^3
  mm_lds(&Gm[0][0], LDC, &P1s[0][0], 8, &P2s[0][0], 8, 16, 16, 8, tid);     // G^2 B
  mm_lds(&M1s[0][0], 16, &Gm[0][0], LDC, &M2s[0][0], 16, 8, 16, 16, tid);   // Gy G^2
  mm_lds(&M1s[0][0], 16, &Bm[0][0], LDK, &S1s[0][0], 8, 8, 16, 8, tid);     // Gy G B
  __syncthreads();
  mm_lds(&G2s[0][0], 16, &G2s[0][0], 16, &G4s[0][0], 16, 16, 16, 16, tid);  // G^4
  mm_lds(&Gm[0][0], LDC, &P2s[0][0], 8, &P3s[0][0], 8, 16, 16, 8, tid);     // G^3 B
  mm_lds(&M2s[0][0], 16, &Gm[0][0], LDC, &M3s[0][0], 16, 8, 16, 16, tid);   // Gy G^3
  mm_lds(&M2s[0][0], 16, &Bm[0][0], LDK, &S2s[0][0], 8, 8, 16, 8, tid);     // Gy G^2 B
  __syncthreads();
  // assemble W (48 rows x 64 padded cols): rows 0..15 z4; 16..23 y1; .. 40..47 y4
  for (int idx = tid; idx < 48 * 64; idx += 64) {
    int rr = idx >> 6, c = idx & 63;
    float val = 0.f;
    if (rr < 16) {
      if (c < 16) val = G4s[rr][c];
      else if (c < 24) val = P3s[rr][c - 16];
      else if (c < 32) val = P2s[rr][c - 24];
      else if (c < 40) val = P1s[rr][c - 32];
      else if (c < 48) val = Bm[rr][c - 40];
    } else if (rr < 24) { int y = rr - 16;
      if (c < 16) val = Gm[16 + y][c];
      else if (c < 24) val = Bm[16 + y][c - 16];
    } else if (rr < 32) { int y = rr - 24;
      if (c < 16) val = M1s[y][c];
      else if (c < 24) val = S0s[y][c - 16];
      else if (c < 32) val = Bm[16 + y][c - 24];
    } else if (rr < 40) { int y = rr - 32;
      if (c < 16) val = M2s[y][c];
      else if (c < 24) val = S1s[y][c - 16];
      else if (c < 32) val = S0s[y][c - 24];
      else if (c < 40) val = Bm[16 + y][c - 32];
    } else { int y = rr - 40;
      if (c < 16) val = M3s[y][c];
      else if (c < 24) val = S2s[y][c - 16];
      else if (c < 32) val = S1s[y][c - 24];
      else if (c < 40) val = S0s[y][c - 32];
      else if (c < 48) val = Bm[16 + y][c - 40];
    }
    gw[COMP_OFF + idx] = val;
  }
  if (tid == 0) ((int*)(gw + HDR_OFF))[0] = na;
}

// ============================================================================
// Phase 2: per-batch recursion. Phase A (t<naA): 1-step, gains streamed from
// gw, readlane broadcasts. Phase B: 4-step composite W rows in registers;
// z-chain (16 readlane+FMA) is the only serial dependence; u-part precomputed
// for group g+1 during group g.
// ============================================================================
#define LOADA(T, GARR) do {                                                    \
    const float* _rp = gw + (size_t)(T) * GAIN_STRIDE + rowsel * 32;           \
    float4 _a = ld4(_rp), _b = ld4(_rp + 4), _c = ld4(_rp + 8);                \
    float4 _d = ld4(_rp + 12), _e = ld4(_rp + 16), _f = ld4(_rp + 20);         \
    GARR[0]=_a.x; GARR[1]=_a.y; GARR[2]=_a.z; GARR[3]=_a.w;                    \
    GARR[4]=_b.x; GARR[5]=_b.y; GARR[6]=_b.z; GARR[7]=_b.w;                    \
    GARR[8]=_c.x; GARR[9]=_c.y; GARR[10]=_c.z; GARR[11]=_c.w;                  \
    GARR[12]=_d.x; GARR[13]=_d.y; GARR[14]=_d.z; GARR[15]=_d.w;                \
    GARR[16]=_e.x; GARR[17]=_e.y; GARR[18]=_e.z; GARR[19]=_e.w;                \
    GARR[20]=_f.x; GARR[21]=_f.y; GARR[22]=_f.z; GARR[23]=_f.w;                \
  } while (0)

#define STEPA(T, GARR, XA) do {                                                \
    float _a0 = 0.f, _a1 = 0.f;                                                \
    _Pragma("unroll") for (int _j = 0; _j < 8; ++_j)  _a0 += GARR[_j] * rdlane(zh, _j); \
    _Pragma("unroll") for (int _j = 8; _j < 16; ++_j) _a1 += GARR[_j] * rdlane(zh, _j); \
    _Pragma("unroll") for (int _m = 0; _m < 8; ++_m)  _a0 += GARR[16 + _m] * rdlane(XA, _m); \
    zh = _a0 + _a1;                                                            \
    if (is_outA) outw[(T) + 1] = zh;                                           \
  } while (0)

#define LOADT(TB, DST) do {                                                    \
    _Pragma("unroll") for (int _i = 0; _i < 4; ++_i) {                         \
      int _ix = (TB) + s4 + _i; if (_ix > TT - 1) _ix = TT - 1;                \
      DST[_i] = xrB[_ix];                                                      \
    }                                                                          \
  } while (0)

#define UACC_INTO(ACC, SRC, P) do {                                            \
    float _u = 0.f;                                                            \
    _Pragma("unroll") for (int _i = 0; _i < 4; ++_i)                           \
      _Pragma("unroll") for (int _m = 0; _m < 8; ++_m)                         \
        _u += w[16 + 8 * _i + _m] * rdlane(SRC[_i], (_m << 3) | (P));          \
    ACC = _u;                                                                  \
  } while (0)

__global__ __launch_bounds__(64)
void mean_kernel(const float* __restrict__ xg, const float* __restrict__ gw,
                 float* __restrict__ outg) {
  const int tid = (int)threadIdx.x;
  const int b = (int)blockIdx.x;

  const int na = ((const int*)(gw + HDR_OFF))[0];
  const int naA = na + ((NSTEP - na) & 3);        // (NSTEP - naA) % 4 == 0

  const int rowsel = (tid < 24) ? tid : 0;
  const bool is_outA = (tid >= 16 && tid < 24);
  const bool is_outB = (tid >= 16 && tid < 48);
  const int orow = is_outB ? ((tid - 16) & 7) : 0;
  const int okoff = is_outB ? ((tid - 16) >> 3) : 0;
  float* outw = outg + ((size_t)b * M + orow) * TT;
  if (is_outA) outw[0] = 0.f;

  const float* xrA = xg + ((size_t)b * M + (tid & 7)) * TT;   // lane m holds x_m[t]
  const float* xrB = xg + ((size_t)b * M + (tid >> 3)) * TT;  // tile row
  const int s4 = (tid & 7) * 4;

  float zh = 0.f;

  // ---------------- phase A ----------------
  {
    float ga[24], gb[24];
    float xa0 = xrA[0], xa1 = xrA[1];
    LOADA(0, ga); LOADA(1, gb);
    int t = 0;
    for (; t + 1 < naA; t += 2) {
      STEPA(t, ga, xa0);
      LOADA(t + 2, ga); xa0 = xrA[t + 2];
      STEPA(t + 1, gb, xa1);
      LOADA(t + 3, gb); xa1 = xrA[t + 3];
    }
    if (t < naA) { STEPA(t, ga, xa0); }
  }

  // ---------------- phase B ----------------
  {
    float w[48];
    const float* wr = gw + COMP_OFF + (size_t)((tid < 48) ? tid : 0) * 64;
    #pragma unroll
    for (int c4 = 0; c4 < 12; ++c4) {
      float4 v = ld4(wr + 4 * c4);
      w[4 * c4 + 0] = v.x; w[4 * c4 + 1] = v.y; w[4 * c4 + 2] = v.z; w[4 * c4 + 3] = v.w;
    }
    float xtc[4], xtn[4];
    LOADT(naA, xtc);
    LOADT(naA + 32, xtn);
    const int NB = (NSTEP - naA) >> 2;
    float uacc;
    UACC_INTO(uacc, xtc, 0);

    for (int g4 = 0; g4 < NB; ++g4) {
      // z-chain: only serial dependence
      float z0 = 0.f, z1 = 0.f;
      #pragma unroll
      for (int j = 0; j < 8; ++j)  z0 += w[j] * rdlane(zh, j);
      #pragma unroll
      for (int j = 8; j < 16; ++j) z1 += w[j] * rdlane(zh, j);
      float znew = z0 + z1 + uacc;

      // prepare u-part for next group (off critical path)
      int gn = g4 + 1;
      if (gn < NB) {
        int pn = gn & 7;
        if (pn == 0) {
          float nua;
          UACC_INTO(nua, xtn, 0);
          #pragma unroll
          for (int i = 0; i < 4; ++i) xtc[i] = xtn[i];
          LOADT(naA + 32 * ((gn >> 3) + 1), xtn);
          uacc = nua;
        } else {
          UACC_INTO(uacc, xtc, pn);
        }
      }

      zh = znew;
      if (is_outB) outw[naA + 4 * g4 + 1 + okoff] = zh;
    }
  }
}

// ============================================================================
// Fallback (round-1 monolithic kernel) if ws is too small.
// ============================================================================
__global__ __launch_bounds__(64)
void kalman_fallback(const float* __restrict__ xg, const float* __restrict__ Fg,
                     const float* __restrict__ Hg, const float* __restrict__ Qg,
                     const float* __restrict__ Rg, float* __restrict__ outg) {
  __shared__ __align__(16) float F_s[D][LDC];
  __shared__ __align__(16) float H_s[M][LDC];
  __shared__ __align__(16) float Q_s[D][LDC];
  __shared__ __align__(16) float R_s[M][8];
  __shared__ __align__(16) float cov[D][LDC];
  __shared__ __align__(16) float Abuf[D][LDC];
  __shared__ __align__(16) float T1[D][LDC];
  __shared__ __align__(16) float T2[D][LDC];
  __shared__ __align__(16) float HC[M][LDC];
  __shared__ __align__(16) float Kmat[D][LDK];
  __shared__ __align__(16) float KR[D][LDK];
  __shared__ __align__(16) float meanv[D];
  __shared__ __align__(16) float mean_u[D];
  __shared__ __align__(16) float residv[M];
  __shared__ __align__(16) float obsv[M];

  const int tid = (int)threadIdx.x;
  const int b   = (int)blockIdx.x;
  const int r  = tid & 15, g  = tid >> 4;
  const int q8 = tid >> 3, c8 = tid & 7;

  for (int idx = tid; idx < D * D; idx += 64) {
    F_s[idx >> 4][idx & 15] = Fg[idx];
    Q_s[idx >> 4][idx & 15] = Qg[idx];
  }
  for (int idx = tid; idx < M * D; idx += 64) H_s[idx >> 4][idx & 15] = Hg[idx];
  if (tid < M * M) R_s[tid >> 3][tid & 7] = Rg[tid];

  st4(&cov[r][4 * g], make_float4(r == 4 * g + 0 ? 1.f : 0.f,
                                  r == 4 * g + 1 ? 1.f : 0.f,
                                  r == 4 * g + 2 ? 1.f : 0.f,
                                  r == 4 * g + 3 ? 1.f : 0.f));
  if (tid < D) meanv[tid] = 0.f;

  const float* xr  = xg  + ((size_t)b * M + (size_t)(tid & 7)) * TT;
  float*       outr = outg + ((size_t)b * M + (size_t)(tid & 7)) * TT;
  float obs_reg = 0.f;
  if (tid < M) { obs_reg = xr[0]; outr[0] = 0.f; }
  __syncthreads();

  for (int t = 0; t < NSTEP; ++t) {
    if (tid < M) obsv[tid] = obs_reg;
    __syncthreads();
    if (tid < M) obs_reg = xr[t + 1];

    {
      float4 h0 = ld4(&H_s[c8][0]), h1 = ld4(&H_s[c8][4]), h2 = ld4(&H_s[c8][8]), h3 = ld4(&H_s[c8][12]);
      float4 m0 = ld4(&meanv[0]), m1 = ld4(&meanv[4]), m2 = ld4(&meanv[8]), m3 = ld4(&meanv[12]);
      float hm = dot4(h0, m0) + dot4(h1, m1) + dot4(h2, m2) + dot4(h3, m3);
      if (tid < M) residv[tid] = obsv[tid] - hm;
    }
    {
      float4 h0 = ld4(&H_s[q8][0]), h1 = ld4(&H_s[q8][4]), h2 = ld4(&H_s[q8][8]), h3 = ld4(&H_s[q8][12]);
      float hk[16] = {h0.x, h0.y, h0.z, h0.w, h1.x, h1.y, h1.z, h1.w,
                      h2.x, h2.y, h2.z, h2.w, h3.x, h3.y, h3.z, h3.w};
      float a0 = 0.f, a1 = 0.f;
      #pragma unroll
      for (int k = 0; k < 16; ++k) {
        float2 cv = *(const float2*)&cov[k][2 * c8];
        a0 += hk[k] * cv.x;
        a1 += hk[k] * cv.y;
      }
      *(float2*)&HC[q8][2 * c8] = make_float2(a0, a1);
    }
    __syncthreads();
    float s0, s1, s2;
    {
      float4 hc0 = ld4(&HC[q8][0]), hc1 = ld4(&HC[q8][4]), hc2 = ld4(&HC[q8][8]), hc3 = ld4(&HC[q8][12]);
      float4 hn0 = ld4(&H_s[c8][0]), hn1 = ld4(&H_s[c8][4]), hn2 = ld4(&H_s[c8][8]), hn3 = ld4(&H_s[c8][12]);
      s0 = R_s[q8][c8] + dot4(hc0, hn0) + dot4(hc1, hn1) + dot4(hc2, hn2) + dot4(hc3, hn3);
      s1 = HC[q8][c8];
      s2 = HC[q8][c8 + 8];
    }
    #pragma unroll
    for (int p = 0; p < 8; ++p) {
      float prow0 = __shfl(s0, (p << 3) | c8, 64);
      float prow1 = __shfl(s1, (p << 3) | c8, 64);
      float prow2 = __shfl(s2, (p << 3) | c8, 64);
      float pivv  = __shfl(s0, (p << 3) | p, 64);
      float fq    = __shfl(s0, (q8 << 3) | p, 64);
      float pinv = 1.0f / pivv;
      float fac = fq * pinv;
      if (q8 == p) { s0 *= pinv; s1 *= pinv; s2 *= pinv; }
      else         { s0 -= fac * prow0; s1 -= fac * prow1; s2 -= fac * prow2; }
    }
    Kmat[c8][q8]     = s1;
    Kmat[c8 + 8][q8] = s2;
    __syncthreads();
    {
      float4 k0 = ld4(&Kmat[r][0]), k1 = ld4(&Kmat[r][4]);
      float kq[8] = {k0.x, k0.y, k0.z, k0.w, k1.x, k1.y, k1.z, k1.w};
      float4 rs0 = ld4(&residv[0]), rs1 = ld4(&residv[4]);
      float mu = meanv[r]
               + kq[0] * rs0.x + kq[1] * rs0.y + kq[2] * rs0.z + kq[3] * rs0.w
               + kq[4] * rs1.x + kq[5] * rs1.y + kq[6] * rs1.z + kq[7] * rs1.w;
      if (tid < D) mean_u[tid] = mu;
      float4 ra0 = ld4(&R_s[2 * g][0]),     ra1 = ld4(&R_s[2 * g][4]);
      float4 rb0 = ld4(&R_s[2 * g + 1][0]), rb1 = ld4(&R_s[2 * g + 1][4]);
      float kr0 = kq[0] * ra0.x + kq[1] * ra0.y + kq[2] * ra0.z + kq[3] * ra0.w
                + kq[4] * ra1.x + kq[5] * ra1.y + kq[6] * ra1.z + kq[7] * ra1.w;
      float kr1 = kq[0] * rb0.x + kq[1] * rb0.y + kq[2] * rb0.z + kq[3] * rb0.w
                + kq[4] * rb1.x + kq[5] * rb1.y + kq[6] * rb1.z + kq[7] * rb1.w;
      *(float2*)&KR[r][2 * g] = make_float2(kr0, kr1);
      float a0 = (r == 4 * g + 0) ? 1.f : 0.f;
      float a1 = (r == 4 * g + 1) ? 1.f : 0.f;
      float a2 = (r == 4 * g + 2) ? 1.f : 0.f;
      float a3 = (r == 4 * g + 3) ? 1.f : 0.f;
      #pragma unroll
      for (int mm = 0; mm < 8; ++mm) {
        float4 hv = ld4(&H_s[mm][4 * g]);
        a0 -= kq[mm] * hv.x; a1 -= kq[mm] * hv.y; a2 -= kq[mm] * hv.z; a3 -= kq[mm] * hv.w;
      }
      st4(&Abuf[r][4 * g], make_float4(a0, a1, a2, a3));
    }
    __syncthreads();
    {
      float4 a0 = ld4(&Abuf[r][0]), a1 = ld4(&Abuf[r][4]), a2 = ld4(&Abuf[r][8]), a3 = ld4(&Abuf[r][12]);
      float av[16] = {a0.x, a0.y, a0.z, a0.w, a1.x, a1.y, a1.z, a1.w,
                      a2.x, a2.y, a2.z, a2.w, a3.x, a3.y, a3.z, a3.w};
      float4 acc = make_float4(0.f, 0.f, 0.f, 0.f);
      #pragma unroll
      for (int k = 0; k < 16; ++k) {
        float4 cv = ld4(&cov[k][4 * g]);
        acc.x += av[k] * cv.x; acc.y += av[k] * cv.y; acc.z += av[k] * cv.z; acc.w += av[k] * cv.w;
      }
      st4(&T1[r][4 * g], acc);
    }
    __syncthreads();
    {
      float cj[4] = {0.f, 0.f, 0.f, 0.f};
      #pragma unroll
      for (int kk = 0; kk < 4; ++kk) {
        float4 acr = ld4(&T1[r][4 * kk]);
        #pragma unroll
        for (int j = 0; j < 4; ++j) {
          float4 aj = ld4(&Abuf[4 * g + j][4 * kk]);
          cj[j] += dot4(acr, aj);
        }
      }
      float4 kr0 = ld4(&KR[r][0]), kr1 = ld4(&KR[r][4]);
      #pragma unroll
      for (int j = 0; j < 4; ++j) {
        float4 kj0 = ld4(&Kmat[4 * g + j][0]), kj1 = ld4(&Kmat[4 * g + j][4]);
        cj[j] += dot4(kr0, kj0) + dot4(kr1, kj1);
      }
      st4(&T2[r][4 * g], make_float4(cj[0], cj[1], cj[2], cj[3]));
    }
    __syncthreads();
    {
      float4 f0 = ld4(&F_s[r][0]), f1 = ld4(&F_s[r][4]), f2 = ld4(&F_s[r][8]), f3 = ld4(&F_s[r][12]);
      float fv[16] = {f0.x, f0.y, f0.z, f0.w, f1.x, f1.y, f1.z, f1.w,
                      f2.x, f2.y, f2.z, f2.w, f3.x, f3.y, f3.z, f3.w};
      float4 acc = make_float4(0.f, 0.f, 0.f, 0.f);
      #pragma unroll
      for (int k = 0; k < 16; ++k) {
        float4 cv = ld4(&T2[k][4 * g]);
        acc.x += fv[k] * cv.x; acc.y += fv[k] * cv.y; acc.z += fv[k] * cv.z; acc.w += fv[k] * cv.w;
      }
      st4(&T1[r][4 * g], acc);
      float4 u0 = ld4(&mean_u[0]), u1 = ld4(&mean_u[4]), u2 = ld4(&mean_u[8]), u3 = ld4(&mean_u[12]);
      float mp = dot4(f0, u0) + dot4(f1, u1) + dot4(f2, u2) + dot4(f3, u3);
      if (tid < D) meanv[tid] = mp;
    }
    __syncthreads();
    {
      float4 fc0 = ld4(&T1[r][0]), fc1 = ld4(&T1[r][4]), fc2 = ld4(&T1[r][8]), fc3 = ld4(&T1[r][12]);
      float4 qv = ld4(&Q_s[r][4 * g]);
      float cj[4];
      #pragma unroll
      for (int j = 0; j < 4; ++j) {
        float4 fj0 = ld4(&F_s[4 * g + j][0]), fj1 = ld4(&F_s[4 * g + j][4]);
        float4 fj2 = ld4(&F_s[4 * g + j][8]), fj3 = ld4(&F_s[4 * g + j][12]);
        cj[j] = dot4(fc0, fj0) + dot4(fc1, fj1) + dot4(fc2, fj2) + dot4(fc3, fj3);
      }
      st4(&cov[r][4 * g], make_float4(cj[0] + qv.x, cj[1] + qv.y, cj[2] + qv.z, cj[3] + qv.w));
      float4 h0 = ld4(&H_s[c8][0]), h1 = ld4(&H_s[c8][4]), h2 = ld4(&H_s[c8][8]), h3 = ld4(&H_s[c8][12]);
      float4 m0 = ld4(&meanv[0]), m1 = ld4(&meanv[4]), m2 = ld4(&meanv[8]), m3 = ld4(&meanv[12]);
      float yv = dot4(h0, m0) + dot4(h1, m1) + dot4(h2, m2) + dot4(h3, m3);
      if (tid < M) outr[t + 1] = yv;
    }
    __syncthreads();
  }
}

} // namespace

extern "C" void kernel_launch(void* const* d_in, const int* in_sizes, int n_in,
                              void* d_out, int out_size, void* d_ws, size_t ws_size,
                              hipStream_t stream) {
  const float* x = (const float*)d_in[0];
  const float* F = (const float*)d_in[1];
  const float* H = (const float*)d_in[2];
  const float* Q = (const float*)d_in[3];
  const float* R = (const float*)d_in[4];
  float* out = (float*)d_out;
  const int bs = in_sizes[0] / (M * TT);

  if (ws_size >= WS_NEED) {
    float* gw = (float*)d_ws;
    hipLaunchKernelGGL(riccati_kernel, dim3(1), dim3(64), 0, stream, F, H, Q, R, gw);
    hipLaunchKernelGGL(mean_kernel, dim3(bs), dim3(64), 0, stream, x, gw, out);
  } else {
    hipLaunchKernelGGL(kalman_fallback, dim3(bs), dim3(64), 0, stream,
                       x, F, H, Q, R, out);
  }
}

// Round 5
// 205.958 us; speedup vs baseline: 29.9383x; 2.0166x over previous
//
#include <hip/hip_runtime.h>

namespace {

constexpr int M  = 8;
constexpr int TT = 2048;
constexpr int D  = 16;
constexpr int NSTEP = TT - 1;     // 2047
constexpr int LDC = 20;
constexpr int LDK = 12;
constexpr int MINRUN = 24;
constexpr int MAXRUN = 128;
constexpr float TOL = 2e-4f;

constexpr int CHUNK = 256;        // output steps per block
constexpr int WARM  = 192;        // warm-up steps (contraction forget)
constexpr int NCHUNK = (NSTEP + CHUNK - 1) / CHUNK;   // 8

// workspace layout (floats)
constexpr int GAIN_STRIDE = 768;              // per-t record: 24 rows x 32
constexpr int PAD = 8;
constexpr int GAIN_SLOTS = MAXRUN + PAD;      // 136
constexpr int K_OFF    = GAIN_SLOTS * GAIN_STRIDE;   // 104448
constexpr int COMP_OFF = K_OFF + MAXRUN * 128;       // 120832
constexpr int HDR_OFF  = COMP_OFF + 48 * 64;         // 123904
constexpr size_t WS_NEED = (size_t)(HDR_OFF + 16) * sizeof(float);

__device__ __forceinline__ float4 ld4(const float* p) { return *(const float4*)p; }
__device__ __forceinline__ void st4(float* p, float4 v) { *(float4*)p = v; }
__device__ __forceinline__ float dot4(float4 a, float4 b) {
  return a.x * b.x + a.y * b.y + a.z * b.z + a.w * b.w;
}
__device__ __forceinline__ float rdlane(float v, int l) {
  return __uint_as_float((unsigned)__builtin_amdgcn_readlane((int)__float_as_uint(v), l));
}

// generic one-time LDS matmul helper (64 lanes cooperate)
__device__ void mm_lds(const float* A, int lda, const float* B, int ldb,
                       float* C, int ldc, int n, int kk, int mcols, int tid) {
  for (int idx = tid; idx < n * mcols; idx += 64) {
    int i = idx / mcols, j = idx - i * mcols;
    float s = 0.f;
    for (int k2 = 0; k2 < kk; ++k2) s += A[i * lda + k2] * B[k2 * ldb + j];
    C[i * ldc + j] = s;
  }
}

// ============================================================================
// Kernel 1: Riccati critical path only (1 block, 1 wave).
// Per iter: HC=H*P ; GJ-solve K ; Pu=P-K*HC ; T=F*Pu ; P=T*F^T+Q (+conv).
// Stores only K_t (16x8 row-major) per step + header na.
// ============================================================================
__global__ __launch_bounds__(64)
void riccati_kernel(const float* __restrict__ Fg, const float* __restrict__ Hg,
                    const float* __restrict__ Qg, const float* __restrict__ Rg,
                    float* __restrict__ gw) {
  __shared__ __align__(16) float F_s[D][LDC], Q_s[D][LDC], H_s[M][LDC], R_s[M][8];
  __shared__ __align__(16) float P[D][LDC], Pu[D][LDC], Tm[D][LDC], HC[M][LDC];
  __shared__ __align__(16) float Km[D][LDK];

  const int tid = (int)threadIdx.x;
  const int r = tid & 15, g = tid >> 4;
  const int q8 = tid >> 3, c8 = tid & 7;

  for (int idx = tid; idx < D * D; idx += 64) {
    F_s[idx >> 4][idx & 15] = Fg[idx];
    Q_s[idx >> 4][idx & 15] = Qg[idx];
  }
  for (int idx = tid; idx < M * D; idx += 64) H_s[idx >> 4][idx & 15] = Hg[idx];
  if (tid < M * M) R_s[tid >> 3][tid & 7] = Rg[tid];
  st4(&P[r][4 * g], make_float4(r == 4 * g + 0 ? 1.f : 0.f,
                                r == 4 * g + 1 ? 1.f : 0.f,
                                r == 4 * g + 2 ? 1.f : 0.f,
                                r == 4 * g + 3 ? 1.f : 0.f));
  __syncthreads();

  int t = 0;
  for (; t < MAXRUN; ++t) {
    // P1: HC = H*P
    {
      float4 h0 = ld4(&H_s[q8][0]), h1 = ld4(&H_s[q8][4]), h2 = ld4(&H_s[q8][8]), h3 = ld4(&H_s[q8][12]);
      float hk[16] = {h0.x, h0.y, h0.z, h0.w, h1.x, h1.y, h1.z, h1.w,
                      h2.x, h2.y, h2.z, h2.w, h3.x, h3.y, h3.z, h3.w};
      float a0 = 0.f, a1 = 0.f;
      #pragma unroll
      for (int k = 0; k < 16; ++k) {
        float2 cv = *(const float2*)&P[k][2 * c8];
        a0 += hk[k] * cv.x; a1 += hk[k] * cv.y;
      }
      *(float2*)&HC[q8][2 * c8] = make_float2(a0, a1);
    }
    __syncthreads();
    // P2: S = HC*H^T + R ; register Gauss-Jordan -> K^T ; store K
    {
      float s0, s1, s2;
      float4 hc0 = ld4(&HC[q8][0]), hc1 = ld4(&HC[q8][4]), hc2 = ld4(&HC[q8][8]), hc3 = ld4(&HC[q8][12]);
      float4 hn0 = ld4(&H_s[c8][0]), hn1 = ld4(&H_s[c8][4]), hn2 = ld4(&H_s[c8][8]), hn3 = ld4(&H_s[c8][12]);
      s0 = R_s[q8][c8] + dot4(hc0, hn0) + dot4(hc1, hn1) + dot4(hc2, hn2) + dot4(hc3, hn3);
      s1 = HC[q8][c8];
      s2 = HC[q8][c8 + 8];
      #pragma unroll
      for (int p = 0; p < 8; ++p) {
        float prow0 = __shfl(s0, (p << 3) | c8, 64);
        float prow1 = __shfl(s1, (p << 3) | c8, 64);
        float prow2 = __shfl(s2, (p << 3) | c8, 64);
        float pivv  = __shfl(s0, (p << 3) | p, 64);
        float fq    = __shfl(s0, (q8 << 3) | p, 64);
        float pinv = 1.0f / pivv;
        float fac = fq * pinv;
        if (q8 == p) { s0 *= pinv; s1 *= pinv; s2 *= pinv; }
        else         { s0 -= fac * prow0; s1 -= fac * prow1; s2 -= fac * prow2; }
      }
      Km[c8][q8]     = s1;       // K[c8][q8]
      Km[c8 + 8][q8] = s2;       // K[c8+8][q8]
      float* gwK = gw + K_OFF + (size_t)t * 128;
      gwK[c8 * 8 + q8]       = s1;
      gwK[(c8 + 8) * 8 + q8] = s2;
    }
    __syncthreads();
    // P3: Pu = P - K*HC
    {
      float4 k0 = ld4(&Km[r][0]), k1 = ld4(&Km[r][4]);
      float kq[8] = {k0.x, k0.y, k0.z, k0.w, k1.x, k1.y, k1.z, k1.w};
      float4 acc = ld4(&P[r][4 * g]);
      #pragma unroll
      for (int m = 0; m < 8; ++m) {
        float4 hc = ld4(&HC[m][4 * g]);
        acc.x -= kq[m] * hc.x; acc.y -= kq[m] * hc.y; acc.z -= kq[m] * hc.z; acc.w -= kq[m] * hc.w;
      }
      st4(&Pu[r][4 * g], acc);
    }
    __syncthreads();
    // P4: T = F*Pu
    {
      float4 f0 = ld4(&F_s[r][0]), f1 = ld4(&F_s[r][4]), f2 = ld4(&F_s[r][8]), f3 = ld4(&F_s[r][12]);
      float fv[16] = {f0.x, f0.y, f0.z, f0.w, f1.x, f1.y, f1.z, f1.w,
                      f2.x, f2.y, f2.z, f2.w, f3.x, f3.y, f3.z, f3.w};
      float4 acc = make_float4(0.f, 0.f, 0.f, 0.f);
      #pragma unroll
      for (int k = 0; k < 16; ++k) {
        float4 cv = ld4(&Pu[k][4 * g]);
        acc.x += fv[k] * cv.x; acc.y += fv[k] * cv.y; acc.z += fv[k] * cv.z; acc.w += fv[k] * cv.w;
      }
      st4(&Tm[r][4 * g], acc);
    }
    __syncthreads();
    // P5: P = T*F^T + Q (+conv)
    int conv;
    {
      float4 t0 = ld4(&Tm[r][0]), t1 = ld4(&Tm[r][4]), t2 = ld4(&Tm[r][8]), t3 = ld4(&Tm[r][12]);
      float cj[4];
      #pragma unroll
      for (int j = 0; j < 4; ++j) {
        cj[j] = dot4(t0, ld4(&F_s[4 * g + j][0])) + dot4(t1, ld4(&F_s[4 * g + j][4]))
              + dot4(t2, ld4(&F_s[4 * g + j][8])) + dot4(t3, ld4(&F_s[4 * g + j][12]));
      }
      float4 qv = ld4(&Q_s[r][4 * g]);
      float4 po = ld4(&P[r][4 * g]);
      float4 pn = make_float4(cj[0] + qv.x, cj[1] + qv.y, cj[2] + qv.z, cj[3] + qv.w);
      st4(&P[r][4 * g], pn);
      float dmax = fmaxf(fmaxf(fabsf(pn.x - po.x), fabsf(pn.y - po.y)),
                         fmaxf(fabsf(pn.z - po.z), fabsf(pn.w - po.w)));
      conv = __all(dmax <= TOL);
    }
    __syncthreads();
    if (t >= MAXRUN - 1 || (t >= MINRUN && conv)) break;
  }
  const int na = (t < MAXRUN ? t : MAXRUN - 1) + 1;   // K stored for [0, na)
  if (tid == 0) ((int*)(gw + HDR_OFF))[0] = na;
}

// ============================================================================
// Kernel 2: per-t gain records (parallel over t). Block j: tt=min(j,na-1);
// B=F*K, G=F-B*H, HG=H*G, HB=H*B -> 24x32 record at gw[j*GAIN_STRIDE].
// Last block also builds the 4-step composite W (48x64) at COMP_OFF.
// ============================================================================
__global__ __launch_bounds__(64)
void gains_kernel(const float* __restrict__ Fg, const float* __restrict__ Hg,
                  float* __restrict__ gw) {
  __shared__ __align__(16) float F_s[D][LDC], H_s[M][LDC], Kt[D][LDK];
  __shared__ __align__(16) float Bm[24][LDK], Gm[24][LDC];
  __shared__ __align__(16) float G2s[16][16], G3s[16][16], G4s[16][16];
  __shared__ __align__(16) float P1s[16][8], P2s[16][8], P3s[16][8];
  __shared__ __align__(16) float M1s[8][16], M2s[8][16], M3s[8][16];
  __shared__ __align__(16) float S0s[8][8], S1s[8][8], S2s[8][8];

  const int tid = (int)threadIdx.x;
  const int j = (int)blockIdx.x;
  const int r = tid & 15, g = tid >> 4;
  const int q8 = tid >> 3, c8 = tid & 7;
  const int na = ((const int*)(gw + HDR_OFF))[0];
  const int tt = (j < na - 1) ? j : (na - 1);

  for (int idx = tid; idx < D * D; idx += 64) F_s[idx >> 4][idx & 15] = Fg[idx];
  for (int idx = tid; idx < M * D; idx += 64) H_s[idx >> 4][idx & 15] = Hg[idx];
  for (int idx = tid; idx < D * M; idx += 64)
    Kt[idx >> 3][idx & 7] = gw[K_OFF + (size_t)tt * 128 + idx];
  __syncthreads();

  // B = F*K  (lane (r,g): cols 2g,2g+1)
  {
    float4 f0 = ld4(&F_s[r][0]), f1 = ld4(&F_s[r][4]), f2 = ld4(&F_s[r][8]), f3 = ld4(&F_s[r][12]);
    float fv[16] = {f0.x, f0.y, f0.z, f0.w, f1.x, f1.y, f1.z, f1.w,
                    f2.x, f2.y, f2.z, f2.w, f3.x, f3.y, f3.z, f3.w};
    float b0 = 0.f, b1 = 0.f;
    #pragma unroll
    for (int k = 0; k < 16; ++k) {
      float2 kv = *(const float2*)&Kt[k][2 * g];
      b0 += fv[k] * kv.x; b1 += fv[k] * kv.y;
    }
    *(float2*)&Bm[r][2 * g] = make_float2(b0, b1);
  }
  __syncthreads();
  // G = F - B*H (lane (r,g): cols 4g..4g+3) ; HB = H*B (lane (q8,c8))
  {
    float4 b0 = ld4(&Bm[r][0]), b1 = ld4(&Bm[r][4]);
    float bq[8] = {b0.x, b0.y, b0.z, b0.w, b1.x, b1.y, b1.z, b1.w};
    float4 g4 = ld4(&F_s[r][4 * g]);
    #pragma unroll
    for (int m = 0; m < 8; ++m) {
      float4 hv = ld4(&H_s[m][4 * g]);
      g4.x -= bq[m] * hv.x; g4.y -= bq[m] * hv.y; g4.z -= bq[m] * hv.z; g4.w -= bq[m] * hv.w;
    }
    st4(&Gm[r][4 * g], g4);
    float hb = 0.f;
    #pragma unroll
    for (int k = 0; k < 16; ++k) hb += H_s[q8][k] * Bm[k][c8];
    Bm[16 + q8][c8] = hb;
  }
  __syncthreads();
  // HG = H*G (lane (q8,c8): cols 2c8,2c8+1)
  {
    float4 h0 = ld4(&H_s[q8][0]), h1 = ld4(&H_s[q8][4]), h2 = ld4(&H_s[q8][8]), h3 = ld4(&H_s[q8][12]);
    float hk[16] = {h0.x, h0.y, h0.z, h0.w, h1.x, h1.y, h1.z, h1.w,
                    h2.x, h2.y, h2.z, h2.w, h3.x, h3.y, h3.z, h3.w};
    float a0 = 0.f, a1 = 0.f;
    #pragma unroll
    for (int k = 0; k < 16; ++k) {
      float2 gv = *(const float2*)&Gm[k][2 * c8];
      a0 += hk[k] * gv.x; a1 += hk[k] * gv.y;
    }
    *(float2*)&Gm[16 + q8][2 * c8] = make_float2(a0, a1);
  }
  __syncthreads();
  // store record j
  if (tid < 24) {
    float* p = gw + (size_t)j * GAIN_STRIDE + tid * 32;
    st4(p + 0,  ld4(&Gm[tid][0]));
    st4(p + 4,  ld4(&Gm[tid][4]));
    st4(p + 8,  ld4(&Gm[tid][8]));
    st4(p + 12, ld4(&Gm[tid][12]));
    st4(p + 16, ld4(&Bm[tid][0]));
    st4(p + 20, ld4(&Bm[tid][4]));
  }

  // last block: build 4-step composite from frozen G,B
  if (j == GAIN_SLOTS - 1) {
    __syncthreads();
    mm_lds(&Gm[0][0], LDC, &Gm[0][0], LDC, &G2s[0][0], 16, 16, 16, 16, tid);  // G^2
    mm_lds(&Gm[0][0], LDC, &Bm[0][0], LDK, &P1s[0][0], 8, 16, 16, 8, tid);    // G B
    mm_lds(&Gm[16][0], LDC, &Gm[0][0], LDC, &M1s[0][0], 16, 8, 16, 16, tid);  // Gy G
    mm_lds(&Gm[16][0], LDC, &Bm[0][0], LDK, &S0s[0][0], 8, 8, 16, 8, tid);    // Gy B
    __syncthreads();
    mm_lds(&G2s[0][0], 16, &Gm[0][0], LDC, &G3s[0][0], 16, 16, 16, 16, tid);  // G^3
    mm_lds(&Gm[0][0], LDC, &P1s[0][0], 8, &P2s[0][0], 8, 16, 16, 8, tid);     // G^2 B
    mm_lds(&M1s[0][0], 16, &Gm[0][0], LDC, &M2s[0][0], 16, 8, 16, 16, tid);   // Gy G^2
    mm_lds(&M1s[0][0], 16, &Bm[0][0], LDK, &S1s[0][0], 8, 8, 16, 8, tid);     // Gy G B
    __syncthreads();
    mm_lds(&G2s[0][0], 16, &G2s[0][0], 16, &G4s[0][0], 16, 16, 16, 16, tid);  // G^4
    mm_lds(&Gm[0][0], LDC, &P2s[0][0], 8, &P3s[0][0], 8, 16, 16, 8, tid);     // G^3 B
    mm_lds(&M2s[0][0], 16, &Gm[0][0], LDC, &M3s[0][0], 16, 8, 16, 16, tid);   // Gy G^3
    mm_lds(&M2s[0][0], 16, &Bm[0][0], LDK, &S2s[0][0], 8, 8, 16, 8, tid);     // Gy G^2 B
    __syncthreads();
    for (int idx = tid; idx < 48 * 64; idx += 64) {
      int rr = idx >> 6, c = idx & 63;
      float val = 0.f;
      if (rr < 16) {
        if (c < 16) val = G4s[rr][c];
        else if (c < 24) val = P3s[rr][c - 16];
        else if (c < 32) val = P2s[rr][c - 24];
        else if (c < 40) val = P1s[rr][c - 32];
        else if (c < 48) val = Bm[rr][c - 40];
      } else if (rr < 24) { int y = rr - 16;
        if (c < 16) val = Gm[16 + y][c];
        else if (c < 24) val = Bm[16 + y][c - 16];
      } else if (rr < 32) { int y = rr - 24;
        if (c < 16) val = M1s[y][c];
        else if (c < 24) val = S0s[y][c - 16];
        else if (c < 32) val = Bm[16 + y][c - 24];
      } else if (rr < 40) { int y = rr - 32;
        if (c < 16) val = M2s[y][c];
        else if (c < 24) val = S1s[y][c - 16];
        else if (c < 32) val = S0s[y][c - 24];
        else if (c < 40) val = Bm[16 + y][c - 32];
      } else { int y = rr - 40;
        if (c < 16) val = M3s[y][c];
        else if (c < 24) val = S2s[y][c - 16];
        else if (c < 32) val = S1s[y][c - 24];
        else if (c < 40) val = S0s[y][c - 32];
        else if (c < 48) val = Bm[16 + y][c - 40];
      }
      gw[COMP_OFF + idx] = val;
    }
  }
}

// ============================================================================
// Kernel 3: chunked mean recursion. Block = (batch, chunk). Chunk c>0 warm-
// starts WARM steps early from z=0 (contraction forgets the init). One-step
// path for transient t<na, 4-step composite otherwise.
// ============================================================================
#define LOADA(T, GARR) do {                                                    \
    const float* _rp = gw + (size_t)(T) * GAIN_STRIDE + rowsel * 32;           \
    float4 _a = ld4(_rp), _b = ld4(_rp + 4), _c = ld4(_rp + 8);                \
    float4 _d = ld4(_rp + 12), _e = ld4(_rp + 16), _f = ld4(_rp + 20);         \
    GARR[0]=_a.x; GARR[1]=_a.y; GARR[2]=_a.z; GARR[3]=_a.w;                    \
    GARR[4]=_b.x; GARR[5]=_b.y; GARR[6]=_b.z; GARR[7]=_b.w;                    \
    GARR[8]=_c.x; GARR[9]=_c.y; GARR[10]=_c.z; GARR[11]=_c.w;                  \
    GARR[12]=_d.x; GARR[13]=_d.y; GARR[14]=_d.z; GARR[15]=_d.w;                \
    GARR[16]=_e.x; GARR[17]=_e.y; GARR[18]=_e.z; GARR[19]=_e.w;                \
    GARR[20]=_f.x; GARR[21]=_f.y; GARR[22]=_f.z; GARR[23]=_f.w;                \
  } while (0)

#define STEPA(T, GARR, XA) do {                                                \
    float _a0 = 0.f, _a1 = 0.f;                                                \
    _Pragma("unroll") for (int _j = 0; _j < 8; ++_j)  _a0 += GARR[_j] * rdlane(zh, _j); \
    _Pragma("unroll") for (int _j = 8; _j < 16; ++_j) _a1 += GARR[_j] * rdlane(zh, _j); \
    _Pragma("unroll") for (int _m = 0; _m < 8; ++_m)  _a0 += GARR[16 + _m] * rdlane(XA, _m); \
    zh = _a0 + _a1;                                                            \
    if (is_outA && (T) + 1 > out_lo) outw[(T) + 1] = zh;                       \
  } while (0)

#define LOADT(TB, DST) do {                                                    \
    _Pragma("unroll") for (int _i = 0; _i < 4; ++_i) {                         \
      int _ix = (TB) + s4 + _i; if (_ix > TT - 1) _ix = TT - 1;                \
      DST[_i] = xrB[_ix];                                                      \
    }                                                                          \
  } while (0)

#define UACC_INTO(ACC, SRC, P) do {                                            \
    float _u = 0.f;                                                            \
    _Pragma("unroll") for (int _i = 0; _i < 4; ++_i)                           \
      _Pragma("unroll") for (int _m = 0; _m < 8; ++_m)                         \
        _u += w[16 + 8 * _i + _m] * rdlane(SRC[_i], (_m << 3) | (P));          \
    ACC = _u;                                                                  \
  } while (0)

__global__ __launch_bounds__(64)
void chunk_kernel(const float* __restrict__ xg, const float* __restrict__ gw,
                  float* __restrict__ outg) {
  const int tid = (int)threadIdx.x;
  const int blk = (int)blockIdx.x;
  const int b = blk >> 3;                  // NCHUNK = 8
  const int c = blk & 7;
  const int na = ((const int*)(gw + HDR_OFF))[0];

  const int out_lo = c * CHUNK;
  const int out_hi = (out_lo + CHUNK < NSTEP) ? (out_lo + CHUNK) : NSTEP;

  const bool is_outB = (tid >= 16 && tid < 48);
  const int orow  = is_outB ? ((tid - 16) & 7) : 0;
  const int okoff = is_outB ? ((tid - 16) >> 3) : 0;
  const bool is_outA = is_outB && (okoff == 0);
  float* outw = outg + ((size_t)b * M + orow) * TT;
  if (c == 0 && is_outA) outw[0] = 0.f;

  const float* xrA = xg + ((size_t)b * M + (tid & 7)) * TT;
  const float* xrB = xg + ((size_t)b * M + (tid >> 3)) * TT;
  const int s4 = (tid & 7) * 4;
  const int rowsel = (tid < 24) ? tid : 0;

  float zh = 0.f;
  int t = (c == 0) ? 0 : (out_lo - WARM);

  // ---- transient one-step phase (t < na), exact per-step gains
  const int oe = (na < out_hi) ? na : out_hi;
  if (t < oe) {
    float ga[24], gb[24];
    float xa0, xa1;
    LOADA((t < na ? t : na), ga);           xa0 = xrA[t];
    LOADA((t + 1 < na ? t + 1 : na), gb);   xa1 = xrA[t + 1];
    for (; t + 1 < oe; t += 2) {
      STEPA(t, ga, xa0);
      LOADA((t + 2 < na ? t + 2 : na), ga); xa0 = xrA[t + 2];
      STEPA(t + 1, gb, xa1);
      LOADA((t + 3 < na ? t + 3 : na), gb); xa1 = xrA[t + 3];
    }
    if (t < oe) { STEPA(t, ga, xa0); ++t; }
  }

  // ---- frozen 4-step composite phase
  if (t < out_hi) {
    float w[48];
    const float* wr = gw + COMP_OFF + (size_t)((tid < 48) ? tid : 0) * 64;
    #pragma unroll
    for (int c4 = 0; c4 < 12; ++c4) {
      float4 v = ld4(wr + 4 * c4);
      w[4 * c4 + 0] = v.x; w[4 * c4 + 1] = v.y; w[4 * c4 + 2] = v.z; w[4 * c4 + 3] = v.w;
    }
    const int t_b0 = t;
    float xtc[4], xtn[4];
    LOADT(t_b0, xtc);
    LOADT(t_b0 + 32, xtn);
    const int NB = (out_hi - t_b0 + 3) >> 2;
    float uacc;
    UACC_INTO(uacc, xtc, 0);

    for (int g4 = 0; g4 < NB; ++g4) {
      float z0 = 0.f, z1 = 0.f;
      #pragma unroll
      for (int jj = 0; jj < 8; ++jj)  z0 += w[jj] * rdlane(zh, jj);
      #pragma unroll
      for (int jj = 8; jj < 16; ++jj) z1 += w[jj] * rdlane(zh, jj);
      float znew = z0 + z1 + uacc;

      int gn = g4 + 1;
      if (gn < NB) {
        int pn = gn & 7;
        if (pn == 0) {
          float nua;
          UACC_INTO(nua, xtn, 0);
          #pragma unroll
          for (int i = 0; i < 4; ++i) xtc[i] = xtn[i];
          LOADT(t_b0 + 32 * ((gn >> 3) + 1), xtn);
          uacc = nua;
        } else {
          UACC_INTO(uacc, xtc, pn);
        }
      }

      zh = znew;
      if (is_outB) {
        int oi = t_b0 + 4 * g4 + 1 + okoff;
        if (oi > out_lo && oi <= out_hi) outw[oi] = zh;
      }
    }
  }
}

// ============================================================================
// Fallback (round-1 monolithic kernel) if ws is too small.
// ============================================================================
__global__ __launch_bounds__(64)
void kalman_fallback(const float* __restrict__ xg, const float* __restrict__ Fg,
                     const float* __restrict__ Hg, const float* __restrict__ Qg,
                     const float* __restrict__ Rg, float* __restrict__ outg) {
  __shared__ __align__(16) float F_s[D][LDC];
  __shared__ __align__(16) float H_s[M][LDC];
  __shared__ __align__(16) float Q_s[D][LDC];
  __shared__ __align__(16) float R_s[M][8];
  __shared__ __align__(16) float cov[D][LDC];
  __shared__ __align__(16) float Abuf[D][LDC];
  __shared__ __align__(16) float T1[D][LDC];
  __shared__ __align__(16) float T2[D][LDC];
  __shared__ __align__(16) float HC[M][LDC];
  __shared__ __align__(16) float Kmat[D][LDK];
  __shared__ __align__(16) float KR[D][LDK];
  __shared__ __align__(16) float meanv[D];
  __shared__ __align__(16) float mean_u[D];
  __shared__ __align__(16) float residv[M];
  __shared__ __align__(16) float obsv[M];

  const int tid = (int)threadIdx.x;
  const int b   = (int)blockIdx.x;
  const int r  = tid & 15, g  = tid >> 4;
  const int q8 = tid >> 3, c8 = tid & 7;

  for (int idx = tid; idx < D * D; idx += 64) {
    F_s[idx >> 4][idx & 15] = Fg[idx];
    Q_s[idx >> 4][idx & 15] = Qg[idx];
  }
  for (int idx = tid; idx < M * D; idx += 64) H_s[idx >> 4][idx & 15] = Hg[idx];
  if (tid < M * M) R_s[tid >> 3][tid & 7] = Rg[tid];

  st4(&cov[r][4 * g], make_float4(r == 4 * g + 0 ? 1.f : 0.f,
                                  r == 4 * g + 1 ? 1.f : 0.f,
                                  r == 4 * g + 2 ? 1.f : 0.f,
                                  r == 4 * g + 3 ? 1.f : 0.f));
  if (tid < D) meanv[tid] = 0.f;

  const float* xr  = xg  + ((size_t)b * M + (size_t)(tid & 7)) * TT;
  float*       outr = outg + ((size_t)b * M + (size_t)(tid & 7)) * TT;
  float obs_reg = 0.f;
  if (tid < M) { obs_reg = xr[0]; outr[0] = 0.f; }
  __syncthreads();

  for (int t = 0; t < NSTEP; ++t) {
    if (tid < M) obsv[tid] = obs_reg;
    __syncthreads();
    if (tid < M) obs_reg = xr[t + 1];

    {
      float4 h0 = ld4(&H_s[c8][0]), h1 = ld4(&H_s[c8][4]), h2 = ld4(&H_s[c8][8]), h3 = ld4(&H_s[c8][12]);
      float4 m0 = ld4(&meanv[0]), m1 = ld4(&meanv[4]), m2 = ld4(&meanv[8]), m3 = ld4(&meanv[12]);
      float hm = dot4(h0, m0) + dot4(h1, m1) + dot4(h2, m2) + dot4(h3, m3);
      if (tid < M) residv[tid] = obsv[tid] - hm;
    }
    {
      float4 h0 = ld4(&H_s[q8][0]), h1 = ld4(&H_s[q8][4]), h2 = ld4(&H_s[q8][8]), h3 = ld4(&H_s[q8][12]);
      float hk[16] = {h0.x, h0.y, h0.z, h0.w, h1.x, h1.y, h1.z, h1.w,
                      h2.x, h2.y, h2.z, h2.w, h3.x, h3.y, h3.z, h3.w};
      float a0 = 0.f, a1 = 0.f;
      #pragma unroll
      for (int k = 0; k < 16; ++k) {
        float2 cv = *(const float2*)&cov[k][2 * c8];
        a0 += hk[k] * cv.x;
        a1 += hk[k] * cv.y;
      }
      *(float2*)&HC[q8][2 * c8] = make_float2(a0, a1);
    }
    __syncthreads();
    float s0, s1, s2;
    {
      float4 hc0 = ld4(&HC[q8][0]), hc1 = ld4(&HC[q8][4]), hc2 = ld4(&HC[q8][8]), hc3 = ld4(&HC[q8][12]);
      float4 hn0 = ld4(&H_s[c8][0]), hn1 = ld4(&H_s[c8][4]), hn2 = ld4(&H_s[c8][8]), hn3 = ld4(&H_s[c8][12]);
      s0 = R_s[q8][c8] + dot4(hc0, hn0) + dot4(hc1, hn1) + dot4(hc2, hn2) + dot4(hc3, hn3);
      s1 = HC[q8][c8];
      s2 = HC[q8][c8 + 8];
    }
    #pragma unroll
    for (int p = 0; p < 8; ++p) {
      float prow0 = __shfl(s0, (p << 3) | c8, 64);
      float prow1 = __shfl(s1, (p << 3) | c8, 64);
      float prow2 = __shfl(s2, (p << 3) | c8, 64);
      float pivv  = __shfl(s0, (p << 3) | p, 64);
      float fq    = __shfl(s0, (q8 << 3) | p, 64);
      float pinv = 1.0f / pivv;
      float fac = fq * pinv;
      if (q8 == p) { s0 *= pinv; s1 *= pinv; s2 *= pinv; }
      else         { s0 -= fac * prow0; s1 -= fac * prow1; s2 -= fac * prow2; }
    }
    Kmat[c8][q8]     = s1;
    Kmat[c8 + 8][q8] = s2;
    __syncthreads();
    {
      float4 k0 = ld4(&Kmat[r][0]), k1 = ld4(&Kmat[r][4]);
      float kq[8] = {k0.x, k0.y, k0.z, k0.w, k1.x, k1.y, k1.z, k1.w};
      float4 rs0 = ld4(&residv[0]), rs1 = ld4(&residv[4]);
      float mu = meanv[r]
               + kq[0] * rs0.x + kq[1] * rs0.y + kq[2] * rs0.z + kq[3] * rs0.w
               + kq[4] * rs1.x + kq[5] * rs1.y + kq[6] * rs1.z + kq[7] * rs1.w;
      if (tid < D) mean_u[tid] = mu;
      float4 ra0 = ld4(&R_s[2 * g][0]),     ra1 = ld4(&R_s[2 * g][4]);
      float4 rb0 = ld4(&R_s[2 * g + 1][0]), rb1 = ld4(&R_s[2 * g + 1][4]);
      float kr0 = kq[0] * ra0.x + kq[1] * ra0.y + kq[2] * ra0.z + kq[3] * ra0.w
                + kq[4] * ra1.x + kq[5] * ra1.y + kq[6] * ra1.z + kq[7] * ra1.w;
      float kr1 = kq[0] * rb0.x + kq[1] * rb0.y + kq[2] * rb0.z + kq[3] * rb0.w
                + kq[4] * rb1.x + kq[5] * rb1.y + kq[6] * rb1.z + kq[7] * rb1.w;
      *(float2*)&KR[r][2 * g] = make_float2(kr0, kr1);
      float a0 = (r == 4 * g + 0) ? 1.f : 0.f;
      float a1 = (r == 4 * g + 1) ? 1.f : 0.f;
      float a2 = (r == 4 * g + 2) ? 1.f : 0.f;
      float a3 = (r == 4 * g + 3) ? 1.f : 0.f;
      #pragma unroll
      for (int mm = 0; mm < 8; ++mm) {
        float4 hv = ld4(&H_s[mm][4 * g]);
        a0 -= kq[mm] * hv.x; a1 -= kq[mm] * hv.y; a2 -= kq[mm] * hv.z; a3 -= kq[mm] * hv.w;
      }
      st4(&Abuf[r][4 * g], make_float4(a0, a1, a2, a3));
    }
    __syncthreads();
    {
      float4 a0 = ld4(&Abuf[r][0]), a1 = ld4(&Abuf[r][4]), a2 = ld4(&Abuf[r][8]), a3 = ld4(&Abuf[r][12]);
      float av[16] = {a0.x, a0.y, a0.z, a0.w, a1.x, a1.y, a1.z, a1.w,
                      a2.x, a2.y, a2.z, a2.w, a3.x, a3.y, a3.z, a3.w};
      float4 acc = make_float4(0.f, 0.f, 0.f, 0.f);
      #pragma unroll
      for (int k = 0; k < 16; ++k) {
        float4 cv = ld4(&cov[k][4 * g]);
        acc.x += av[k] * cv.x; acc.y += av[k] * cv.y; acc.z += av[k] * cv.z; acc.w += av[k] * cv.w;
      }
      st4(&T1[r][4 * g], acc);
    }
    __syncthreads();
    {
      float cj[4] = {0.f, 0.f, 0.f, 0.f};
      #pragma unroll
      for (int kk = 0; kk < 4; ++kk) {
        float4 acr = ld4(&T1[r][4 * kk]);
        #pragma unroll
        for (int j = 0; j < 4; ++j) {
          float4 aj = ld4(&Abuf[4 * g + j][4 * kk]);
          cj[j] += dot4(acr, aj);
        }
      }
      float4 kr0 = ld4(&KR[r][0]), kr1 = ld4(&KR[r][4]);
      #pragma unroll
      for (int j = 0; j < 4; ++j) {
        float4 kj0 = ld4(&Kmat[4 * g + j][0]), kj1 = ld4(&Kmat[4 * g + j][4]);
        cj[j] += dot4(kr0, kj0) + dot4(kr1, kj1);
      }
      st4(&T2[r][4 * g], make_float4(cj[0], cj[1], cj[2], cj[3]));
    }
    __syncthreads();
    {
      float4 f0 = ld4(&F_s[r][0]), f1 = ld4(&F_s[r][4]), f2 = ld4(&F_s[r][8]), f3 = ld4(&F_s[r][12]);
      float fv[16] = {f0.x, f0.y, f0.z, f0.w, f1.x, f1.y, f1.z, f1.w,
                      f2.x, f2.y, f2.z, f2.w, f3.x, f3.y, f3.z, f3.w};
      float4 acc = make_float4(0.f, 0.f, 0.f, 0.f);
      #pragma unroll
      for (int k = 0; k < 16; ++k) {
        float4 cv = ld4(&T2[k][4 * g]);
        acc.x += fv[k] * cv.x; acc.y += fv[k] * cv.y; acc.z += fv[k] * cv.z; acc.w += fv[k] * cv.w;
      }
      st4(&T1[r][4 * g], acc);
      float4 u0 = ld4(&mean_u[0]), u1 = ld4(&mean_u[4]), u2 = ld4(&mean_u[8]), u3 = ld4(&mean_u[12]);
      float mp = dot4(f0, u0) + dot4(f1, u1) + dot4(f2, u2) + dot4(f3, u3);
      if (tid < D) meanv[tid] = mp;
    }
    __syncthreads();
    {
      float4 fc0 = ld4(&T1[r][0]), fc1 = ld4(&T1[r][4]), fc2 = ld4(&T1[r][8]), fc3 = ld4(&T1[r][12]);
      float4 qv = ld4(&Q_s[r][4 * g]);
      float cj[4];
      #pragma unroll
      for (int j = 0; j < 4; ++j) {
        float4 fj0 = ld4(&F_s[4 * g + j][0]), fj1 = ld4(&F_s[4 * g + j][4]);
        float4 fj2 = ld4(&F_s[4 * g + j][8]), fj3 = ld4(&F_s[4 * g + j][12]);
        cj[j] = dot4(fc0, fj0) + dot4(fc1, fj1) + dot4(fc2, fj2) + dot4(fc3, fj3);
      }
      st4(&cov[r][4 * g], make_float4(cj[0] + qv.x, cj[1] + qv.y, cj[2] + qv.z, cj[3] + qv.w));
      float4 h0 = ld4(&H_s[c8][0]), h1 = ld4(&H_s[c8][4]), h2 = ld4(&H_s[c8][8]), h3 = ld4(&H_s[c8][12]);
      float4 m0 = ld4(&meanv[0]), m1 = ld4(&meanv[4]), m2 = ld4(&meanv[8]), m3 = ld4(&meanv[12]);
      float yv = dot4(h0, m0) + dot4(h1, m1) + dot4(h2, m2) + dot4(h3, m3);
      if (tid < M) outr[t + 1] = yv;
    }
    __syncthreads();
  }
}

} // namespace

extern "C" void kernel_launch(void* const* d_in, const int* in_sizes, int n_in,
                              void* d_out, int out_size, void* d_ws, size_t ws_size,
                              hipStream_t stream) {
  const float* x = (const float*)d_in[0];
  const float* F = (const float*)d_in[1];
  const float* H = (const float*)d_in[2];
  const float* Q = (const float*)d_in[3];
  const float* R = (const float*)d_in[4];
  float* out = (float*)d_out;
  const int bs = in_sizes[0] / (M * TT);

  if (ws_size >= WS_NEED) {
    float* gw = (float*)d_ws;
    hipLaunchKernelGGL(riccati_kernel, dim3(1), dim3(64), 0, stream, F, H, Q, R, gw);
    hipLaunchKernelGGL(gains_kernel, dim3(GAIN_SLOTS), dim3(64), 0, stream, F, H, gw);
    hipLaunchKernelGGL(chunk_kernel, dim3(bs * NCHUNK), dim3(64), 0, stream, x, gw, out);
  } else {
    hipLaunchKernelGGL(kalman_fallback, dim3(bs), dim3(64), 0, stream,
                       x, F, H, Q, R, out);
  }
}